// Round 1
// baseline (290.665 us; speedup 1.0000x reference)
//
#include <hip/hip_runtime.h>
#include <stdint.h>
#include <stddef.h>

typedef __bf16 bf16;
typedef __attribute__((ext_vector_type(8))) __bf16 bf16x8;
typedef __attribute__((ext_vector_type(4))) __bf16 bf16x4;
typedef __attribute__((ext_vector_type(4))) float f32x4;
typedef __attribute__((ext_vector_type(4))) float float4v;

#define BATCH 4
#define SEQ   2048
#define EMB   1024
#define NH    16
#define HD    64
#define F3    3072   // 3*EMB

#define MFMA16(a, b, c) __builtin_amdgcn_mfma_f32_16x16x32_bf16((a), (b), (c), 0, 0, 0)

// async global->LDS, 16B per lane. lds ptr must be wave-uniform; lane i lands at l + i*16B.
__device__ __forceinline__ void gload_lds16(const bf16* g, bf16* l) {
  __builtin_amdgcn_global_load_lds(
      (const __attribute__((address_space(1))) uint32_t*)g,
      (__attribute__((address_space(3))) uint32_t*)l, 16, 0, 0);
}

__device__ __forceinline__ int mod10(int x) { return x >= 10 ? x - 10 : x; }  // x < 20

// ---------------------------------------------------------------------------
// RoPE table: cos/sin[pos][d1] for pos<2048, d1<32, f32 (ref keeps f32).
// ---------------------------------------------------------------------------
__global__ __launch_bounds__(256) void rope_table(float* __restrict__ cosT,
                                                  float* __restrict__ sinT) {
  int idx = blockIdx.x * 256 + threadIdx.x;   // 65536
  int pos = idx >> 5, d1 = idx & 31;
  float inv = powf(10000.0f, -(float)(2 * d1) / 64.0f);
  float th = (float)pos * inv;
  cosT[idx] = cosf(th);
  sinT[idx] = sinf(th);
}

// ---------------------------------------------------------------------------
// Convert f32 -> bf16. n4 = count/4.
// ---------------------------------------------------------------------------
__global__ __launch_bounds__(256) void convert_bf16(const float* __restrict__ src,
                                                    bf16* __restrict__ dst, int n4) {
  int i = blockIdx.x * 256 + threadIdx.x;
  if (i >= n4) return;
  float4v v = ((const float4v*)src)[i];
  bf16x4 o;
#pragma unroll
  for (int k = 0; k < 4; ++k) o[k] = (bf16)v[k];
  ((bf16x4*)dst)[i] = o;
}

// ---------------------------------------------------------------------------
// Transpose + convert: in [R][C] f32 -> out [C][R] bf16.
// ---------------------------------------------------------------------------
__global__ __launch_bounds__(256) void transpose_f32_bf16(const float* __restrict__ in,
                                                          bf16* __restrict__ out,
                                                          int R, int C) {
  __shared__ bf16 tile[32][33];
  const int tx = threadIdx.x & 31;
  const int ty = threadIdx.x >> 5;  // 0..7
  const int c0 = blockIdx.x * 32, r0 = blockIdx.y * 32;
#pragma unroll
  for (int kk = 0; kk < 4; ++kk) {
    int r = ty + kk * 8;
    tile[r][tx] = (bf16)in[(size_t)(r0 + r) * C + c0 + tx];
  }
  __syncthreads();
#pragma unroll
  for (int kk = 0; kk < 4; ++kk) {
    int r = ty + kk * 8;
    out[(size_t)(c0 + r) * R + r0 + tx] = tile[tx][r];
  }
}

// ---------------------------------------------------------------------------
// 256x256 / BK=64 8-phase MFMA GEMM core (HK-style schedule, plain HIP).
//  - 512 threads = 8 waves (2M x 4N); per-wave C = 128x64 -> acc[8][4] f32x4.
//  - LDS: ring of 10 half-tile slots x 16KB = 160KB dynamic.
//    half-tile = 128 rows x 64 k bf16, T2 XOR swizzle: 16B-granule ^= (row&7).
//  - staging: global_load_lds width=16 with PRE-SWIZZLED global src (linear
//    LDS dest), exactly the attn kernel's proven sw8 pattern.
//  - ring schedule: tile t reads slots (4t..4t+3)%10; phase q stages
//    ht=4t+6+q into slot (4t+6+q)%10  (B of t+1 at q=0,1; A of t+2 at q=2,3).
//    Stages never touch live slots; vmcnt(4) once/tile => next tile landed.
//  - per phase: {ds_read subtile | stage half-tile} -> barrier ->
//    lgkmcnt(0) -> setprio(1) 16xMFMA setprio(0) -> barrier. (T3+T4+T5)
//  - K fixed at EMB=1024 -> 16 K-tiles; A,B row stride = EMB.
// ---------------------------------------------------------------------------
__device__ __forceinline__ void gemm256_core(bf16* lds,
                                             const bf16* __restrict__ Abase,
                                             const bf16* __restrict__ Bbase,
                                             f32x4 (&acc)[8][4]) {
  const int tid = threadIdx.x;
  const int w = tid >> 6, lane = tid & 63;
  const int lhi = lane >> 4, llo = lane & 15, l7 = llo & 7;
  const int wr = w >> 2, wc = w & 3;          // 2M x 4N wave grid
  const int srow = lane >> 3;                 // staging row within 8-row chunk
  const int sk16 = (lane & 7) ^ srow;         // pre-swizzled global 16B granule
  const size_t g_lane = (size_t)(w * 16 + srow) * EMB + sk16 * 8;
  bf16* ldsw = lds + w * 1024;                // wave chunk base within a slot

  // swizzled k-offsets (elements) for the two K=32 chunks of a BK=64 tile
  const int ka0 = (lhi * 8) ^ (l7 << 3);
  const int ka1 = (32 + lhi * 8) ^ (l7 << 3);
  const int arow = llo * 64;                        // A frag row base (elems)
  const int brow = ((wc & 1) * 64 + llo) * 64;      // B frag row base (elems)

#pragma unroll
  for (int i = 0; i < 8; ++i)
#pragma unroll
    for (int j = 0; j < 4; ++j) acc[i][j] = (f32x4){0.f, 0.f, 0.f, 0.f};

#define STAGE(baseptr, slot)                              \
  do {                                                    \
    const bf16* _b = (baseptr);                           \
    bf16* _l = ldsw + (slot) * 8192;                      \
    gload_lds16(_b + g_lane, _l);                         \
    gload_lds16(_b + g_lane + 8 * EMB, _l + 512);         \
  } while (0)

  // prologue: ht0..5 = t0.Ah0, t0.Ah1, t0.Bh0, t0.Bh1, t1.Ah0, t1.Ah1
  STAGE(Abase, 0);
  STAGE(Abase + 128 * EMB, 1);
  STAGE(Bbase, 2);
  STAGE(Bbase + 128 * EMB, 3);
  STAGE(Abase + 64, 4);
  STAGE(Abase + 128 * EMB + 64, 5);
  asm volatile("s_waitcnt vmcnt(4)" ::: "memory");  // tile 0 landed (4 newest = t1.A)
  __builtin_amdgcn_s_barrier();

  int rs = 0;  // (4t) % 10
#pragma unroll 1
  for (int t = 0; t < 16; ++t) {
    const bf16* ldsA = lds + mod10(rs + wr) * 8192 + arow;
    const bf16* ldsB = lds + mod10(rs + 2 + (wc >> 1)) * 8192 + brow;
    const int k1 = (t + 1) * 64;
    const int k2 = (t + 2) * 64;
    bf16x8 a[4][2], b0[2][2], b1[2][2];

    // ---- phase 0: (mh0, nh0) -> acc[0..3][0..1]
#pragma unroll
    for (int i = 0; i < 4; ++i) {
      a[i][0] = *(const bf16x8*)(ldsA + i * 1024 + ka0);
      a[i][1] = *(const bf16x8*)(ldsA + i * 1024 + ka1);
    }
#pragma unroll
    for (int j = 0; j < 2; ++j) {
      b0[j][0] = *(const bf16x8*)(ldsB + j * 1024 + ka0);
      b0[j][1] = *(const bf16x8*)(ldsB + j * 1024 + ka1);
    }
    if (t < 15) STAGE(Bbase + k1, mod10(rs + 6));
    __builtin_amdgcn_s_barrier();
    asm volatile("s_waitcnt lgkmcnt(0)" ::: "memory");
    __builtin_amdgcn_sched_barrier(0);
    __builtin_amdgcn_s_setprio(1);
#pragma unroll
    for (int i = 0; i < 4; ++i)
#pragma unroll
      for (int j = 0; j < 2; ++j) {
        acc[i][j] = MFMA16(a[i][0], b0[j][0], acc[i][j]);
        acc[i][j] = MFMA16(a[i][1], b0[j][1], acc[i][j]);
      }
    __builtin_amdgcn_s_setprio(0);
    __builtin_amdgcn_s_barrier();

    // ---- phase 1: (mh0, nh1) -> acc[0..3][2..3]
#pragma unroll
    for (int j = 0; j < 2; ++j) {
      b1[j][0] = *(const bf16x8*)(ldsB + 2048 + j * 1024 + ka0);
      b1[j][1] = *(const bf16x8*)(ldsB + 2048 + j * 1024 + ka1);
    }
    if (t < 15) STAGE(Bbase + 128 * EMB + k1, mod10(rs + 7));
    __builtin_amdgcn_s_barrier();
    asm volatile("s_waitcnt lgkmcnt(0)" ::: "memory");
    __builtin_amdgcn_sched_barrier(0);
    __builtin_amdgcn_s_setprio(1);
#pragma unroll
    for (int i = 0; i < 4; ++i)
#pragma unroll
      for (int j = 0; j < 2; ++j) {
        acc[i][2 + j] = MFMA16(a[i][0], b1[j][0], acc[i][2 + j]);
        acc[i][2 + j] = MFMA16(a[i][1], b1[j][1], acc[i][2 + j]);
      }
    __builtin_amdgcn_s_setprio(0);
    __builtin_amdgcn_s_barrier();

    // ---- phase 2: (mh1, nh1) -> acc[4..7][2..3]
#pragma unroll
    for (int i = 0; i < 4; ++i) {
      a[i][0] = *(const bf16x8*)(ldsA + 4096 + i * 1024 + ka0);
      a[i][1] = *(const bf16x8*)(ldsA + 4096 + i * 1024 + ka1);
    }
    if (t < 14) STAGE(Abase + k2, mod10(rs + 8));
    __builtin_amdgcn_s_barrier();
    asm volatile("s_waitcnt lgkmcnt(0)" ::: "memory");
    __builtin_amdgcn_sched_barrier(0);
    __builtin_amdgcn_s_setprio(1);
#pragma unroll
    for (int i = 0; i < 4; ++i)
#pragma unroll
      for (int j = 0; j < 2; ++j) {
        acc[4 + i][2 + j] = MFMA16(a[i][0], b1[j][0], acc[4 + i][2 + j]);
        acc[4 + i][2 + j] = MFMA16(a[i][1], b1[j][1], acc[4 + i][2 + j]);
      }
    __builtin_amdgcn_s_setprio(0);
    __builtin_amdgcn_s_barrier();

    // ---- phase 3: (mh1, nh0) -> acc[4..7][0..1]  (reuses a from ph2, b0 from ph0)
    if (t < 14) STAGE(Abase + 128 * EMB + k2, mod10(rs + 9));
    __builtin_amdgcn_s_barrier();
    asm volatile("s_waitcnt lgkmcnt(0)" ::: "memory");
    __builtin_amdgcn_sched_barrier(0);
    __builtin_amdgcn_s_setprio(1);
#pragma unroll
    for (int i = 0; i < 4; ++i)
#pragma unroll
      for (int j = 0; j < 2; ++j) {
        acc[4 + i][j] = MFMA16(a[i][0], b0[j][0], acc[4 + i][j]);
        acc[4 + i][j] = MFMA16(a[i][1], b0[j][1], acc[4 + i][j]);
      }
    __builtin_amdgcn_s_setprio(0);
    // counted drain (T4): next tile's 4 half-tiles complete, 2 newest may fly
    if (t < 14) {
      asm volatile("s_waitcnt vmcnt(4)" ::: "memory");
    } else if (t == 14) {
      asm volatile("s_waitcnt vmcnt(0)" ::: "memory");
    }
    if (t < 15) __builtin_amdgcn_s_barrier();

    rs += 4;
    if (rs >= 10) rs -= 10;
  }
#undef STAGE
}

// ---------------------------------------------------------------------------
// QKV GEMM (8-phase 256^2 core) + bias + RoPE + scatter epilogue.
// Grid 384 (32 Mtiles x 12 Ntiles), XCD-bijective swizzle (384 % 8 == 0).
// ---------------------------------------------------------------------------
__global__ __launch_bounds__(512, 2) void qkv8_kernel(
    const bf16* __restrict__ x, const bf16* __restrict__ wT,
    const float* __restrict__ bias, bf16* __restrict__ qo, bf16* __restrict__ ko,
    bf16* __restrict__ vo, const float* __restrict__ cosT,
    const float* __restrict__ sinT) {
  extern __shared__ __align__(16) bf16 ldsb[];
  const int orig = blockIdx.x;
  const int wg = (orig & 7) * 48 + (orig >> 3);   // 48 contiguous wgs per XCD
  const int bx = wg % 12, by = wg / 12;
  const int row_a0 = by * 256, row_b0 = bx * 256;

  f32x4 acc[8][4];
  gemm256_core(ldsb, x + (size_t)row_a0 * EMB, wT + (size_t)row_b0 * EMB, acc);

  const int tid = threadIdx.x;
  const int w = tid >> 6, lane = tid & 63;
  const int lhi = lane >> 4, llo = lane & 15;
  const int wr = w >> 2, wc = w & 3;

  const int f0 = row_b0 + wc * 64;      // wave col base, 64-aligned
  const int part = f0 >> 10;            // 0=Q 1=K 2=V
  const int hh = (f0 & 1023) >> 6;      // head
  const int m_base = row_a0 + wr * 128;

  float bvals[4];
#pragma unroll
  for (int j = 0; j < 4; ++j) bvals[j] = bias[f0 + j * 16 + llo];

  if (part == 2) {
#pragma unroll
    for (int mi = 0; mi < 8; ++mi) {
      int m0 = m_base + mi * 16 + lhi * 4;
      int bb = m0 >> 11, pos0 = m0 & 2047;
#pragma unroll
      for (int j = 0; j < 4; ++j) {
        int dd = j * 16 + llo;
        bf16x4 pk;
#pragma unroll
        for (int r = 0; r < 4; ++r) pk[r] = (bf16)(acc[mi][j][r] + bvals[j]);
        *(bf16x4*)(vo + ((size_t)(bb * NH + hh) * HD + dd) * SEQ + pos0) = pk;
      }
    }
  } else {
    bf16* dst = (part == 0) ? qo : ko;
    const float qs = (part == 0) ? 0.125f : 1.0f;  // fold 1/sqrt(64) into Q (exact pow2)
#pragma unroll
    for (int mi = 0; mi < 8; ++mi) {
#pragma unroll
      for (int r = 0; r < 4; ++r) {
        int m = m_base + mi * 16 + lhi * 4 + r;
        int bb = m >> 11, pos = m & 2047;
        size_t base = ((size_t)(bb * NH + hh) * SEQ + pos) * HD;
#pragma unroll
        for (int j = 0; j < 2; ++j) {
          int d1 = j * 16 + llo;
          float x1 = acc[mi][j][r] + bvals[j];
          float x2 = acc[mi][j + 2][r] + bvals[j + 2];
          float cth = cosT[pos * 32 + d1];
          float sth = sinT[pos * 32 + d1];
          dst[base + d1] = (bf16)((x1 * cth - x2 * sth) * qs);
          dst[base + d1 + 32] = (bf16)((x2 * cth + x1 * sth) * qs);
        }
      }
    }
  }
}

// ---------------------------------------------------------------------------
// Output projection on the same 8-phase core. Grid 128 (32 x 4), swizzled.
// ---------------------------------------------------------------------------
__global__ __launch_bounds__(512, 2) void outproj8_kernel(
    const bf16* __restrict__ a_in, const bf16* __restrict__ wT,
    const float* __restrict__ bo, float* __restrict__ out) {
  extern __shared__ __align__(16) bf16 ldsb[];
  const int orig = blockIdx.x;
  const int wg = (orig & 7) * 16 + (orig >> 3);   // 128 % 8 == 0
  const int bx = wg % 4, by = wg / 4;
  const int row_a0 = by * 256, row_b0 = bx * 256;

  f32x4 acc[8][4];
  gemm256_core(ldsb, a_in + (size_t)row_a0 * EMB, wT + (size_t)row_b0 * EMB, acc);

  const int tid = threadIdx.x;
  const int w = tid >> 6, lane = tid & 63;
  const int lhi = lane >> 4, llo = lane & 15;
  const int wr = w >> 2, wc = w & 3;

  const int col0 = row_b0 + wc * 64;
  const int m_base = row_a0 + wr * 128;
  float bvals[4];
#pragma unroll
  for (int j = 0; j < 4; ++j) bvals[j] = bo[col0 + j * 16 + llo];
#pragma unroll
  for (int mi = 0; mi < 8; ++mi) {
#pragma unroll
    for (int r = 0; r < 4; ++r) {
      int m = m_base + mi * 16 + lhi * 4 + r;
#pragma unroll
      for (int j = 0; j < 4; ++j)
        out[(size_t)m * EMB + col0 + j * 16 + llo] = acc[mi][j][r] + bvals[j];
    }
  }
}

// ---------------------------------------------------------------------------
// Flash attention v4 (unchanged - known-good): 512-thread blocks, BK=64,
// double-buffered K/V, one barrier/tile, transposed-score MFMA.
// ---------------------------------------------------------------------------
__global__ __launch_bounds__(512) void attn_kernel(const bf16* __restrict__ q,
                                                   const bf16* __restrict__ k,
                                                   const bf16* __restrict__ vT,
                                                   bf16* __restrict__ o) {
  __shared__ __align__(16) bf16 smem[32768];
  bf16* Qs = smem;

  const int tid = threadIdx.x, w = tid >> 6, lane = tid & 63;
  const int lhi = lane >> 4, llo = lane & 15;
  const int l7 = llo & 7;
  const int bidx = blockIdx.x;
  const int vblk = (bidx & 7) * 64 + (bidx >> 3);  // XCD-contiguous remap (512 blocks)
  const int qt = vblk & 7, bh = vblk >> 3;         // 8 q-tiles of 256, bh in [0,64)
  const bf16* qbase = q + (size_t)bh * SEQ * HD + qt * 256 * HD;
  const bf16* kbase = k + (size_t)bh * SEQ * HD;
  const bf16* vbase = vT + (size_t)bh * HD * SEQ;
  bf16* Pw = smem + w * 2048;   // wave-private 32q x 64tok P (overlays own Q rows)

  const int rowc = lane >> 3;                     // row within 8-row chunk
  const int sw8 = (lane & 7) ^ rowc;              // staging XOR swizzle (16B granules)

  // stage Q (4 chunks/wave, 256 rows total); waves 0-3: K0, waves 4-7: V0
#pragma unroll
  for (int c = 0; c < 4; ++c) {
    int chunk = w * 4 + c;
    int row = chunk * 8 + rowc;
    gload_lds16(qbase + (size_t)row * HD + sw8 * 8, &Qs[chunk * 512]);
  }
  if (w < 4) {
#pragma unroll
    for (int c = 0; c < 2; ++c) {
      int chunk = w * 2 + c;
      int row = chunk * 8 + rowc;
      gload_lds16(kbase + (size_t)row * HD + sw8 * 8, &smem[16384 + chunk * 512]);
    }
  } else {
#pragma unroll
    for (int c = 0; c < 2; ++c) {
      int chunk = (w - 4) * 2 + c;
      int row = chunk * 8 + rowc;
      gload_lds16(vbase + (size_t)row * SEQ + sw8 * 8, &smem[24576 + chunk * 512]);
    }
  }
  __syncthreads();

  bf16x8 qf[2][2];
#pragma unroll
  for (int i = 0; i < 2; ++i)
#pragma unroll
    for (int kc = 0; kc < 2; ++kc)
      qf[i][kc] = *(const bf16x8*)&Qs[(w * 32 + i * 16 + llo) * 64 +
                                      (((kc * 4 + lhi) ^ l7) * 8)];
  __syncthreads();  // q-frag reads complete before first P write

  float rsum[2] = {0.f, 0.f};
  f32x4 oacc[2][4];
#pragma unroll
  for (int i = 0; i < 2; ++i)
#pragma unroll
    for (int j = 0; j < 4; ++j) oacc[i][j] = (f32x4){0.f, 0.f, 0.f, 0.f};

  for (int kb = 0; kb < 32; ++kb) {
    bf16* Kc = smem + 16384 + (kb & 1) * 4096;
    bf16* Vc = smem + 24576 + (kb & 1) * 4096;
    // prefetch next tile into alt buffers (lands during this tile's compute)
    if (kb < 31) {
      int kpos = (kb + 1) * 64;
      if (w < 4) {
        bf16* Kn = smem + 16384 + ((kb + 1) & 1) * 4096;
#pragma unroll
        for (int c = 0; c < 2; ++c) {
          int chunk = w * 2 + c;
          int row = chunk * 8 + rowc;
          gload_lds16(kbase + (size_t)(kpos + row) * HD + sw8 * 8, &Kn[chunk * 512]);
        }
      } else {
        bf16* Vn = smem + 24576 + ((kb + 1) & 1) * 4096;
#pragma unroll
        for (int c = 0; c < 2; ++c) {
          int chunk = (w - 4) * 2 + c;
          int row = chunk * 8 + rowc;
          gload_lds16(vbase + (size_t)row * SEQ + kpos + sw8 * 8, &Vn[chunk * 512]);
        }
      }
    }
    // S^T = K Q^T: A=K (tokens x dims), B=Q^T. D[tok][q]: lane holds, per
    // (tt,i), 4 consecutive tokens (lhi*4+r) of q-row i*16+llo.
    f32x4 st[4][2];
#pragma unroll
    for (int tt = 0; tt < 4; ++tt)
#pragma unroll
      for (int i = 0; i < 2; ++i) st[tt][i] = (f32x4){0.f, 0.f, 0.f, 0.f};
#pragma unroll
    for (int kc = 0; kc < 2; ++kc) {
      bf16x8 kfr[4];
#pragma unroll
      for (int tt = 0; tt < 4; ++tt)
        kfr[tt] = *(const bf16x8*)&Kc[(tt * 16 + llo) * 64 +
                                      (((kc * 4 + lhi) ^ l7) * 8)];
#pragma unroll
      for (int tt = 0; tt < 4; ++tt)
#pragma unroll
        for (int i = 0; i < 2; ++i)
          st[tt][i] = MFMA16(kfr[tt], qf[i][kc], st[tt][i]);
    }
    // streaming softmax: p = exp(s) (prescaled by 1/8 via Q); packed b64 P
    // writes into q-major P layout [32q][64tok], 8B-granule XOR swizzle.
#pragma unroll
    for (int tt = 0; tt < 4; ++tt) {
#pragma unroll
      for (int i = 0; i < 2; ++i) {
        bf16x4 pk;
        float a = 0.f;
#pragma unroll
        for (int r = 0; r < 4; ++r) {
          float p = __expf(st[tt][i][r]);
          pk[r] = (bf16)p;
          a += p;
        }
        rsum[i] += a;
        int gi = (tt * 4 + lhi) ^ (l7 << 1);
        *(bf16x4*)&Pw[(i * 16 + llo) * 64 + gi * 4] = pk;
      }
    }
    // O += P V  (P A-operand from q-major LDS; V^T rows token-contiguous)
#pragma unroll
    for (int kc = 0; kc < 2; ++kc) {
      bf16x8 af[2], bv[4];
      int xg = ((kc * 4 + lhi) ^ l7) * 8;
      int pg = ((kc * 8 + lhi * 2) ^ (l7 << 1)) * 4;
#pragma unroll
      for (int i = 0; i < 2; ++i)
        af[i] = *(const bf16x8*)&Pw[(i * 16 + llo) * 64 + pg];
#pragma unroll
      for (int jd = 0; jd < 4; ++jd)
        bv[jd] = *(const bf16x8*)&Vc[(jd * 16 + llo) * 64 + xg];
#pragma unroll
      for (int i = 0; i < 2; ++i)
#pragma unroll
        for (int jd = 0; jd < 4; ++jd) oacc[i][jd] = MFMA16(af[i], bv[jd], oacc[i][jd]);
    }
    __syncthreads();  // end of tile: prefetch landed + guards buffer reuse
  }

  // epilogue: lane holds rsum for q=i*16+llo over its 16 tokens; reduce over
  // lhi lanes (xor 16,32), redistribute to oacc row owners via shfl, write.
  const int bb = bh >> 4, hh = bh & 15;
#pragma unroll
  for (int i = 0; i < 2; ++i) {
    float t = rsum[i];
    t += __shfl_xor(t, 16);
    t += __shfl_xor(t, 32);
#pragma unroll
    for (int r = 0; r < 4; ++r) {
      float l = __shfl(t, lhi * 4 + r);   // total for q-row i*16+lhi*4+r
      float inv = 1.0f / l;
      int pos = qt * 256 + w * 32 + i * 16 + lhi * 4 + r;
      size_t base = ((size_t)bb * SEQ + pos) * EMB + hh * HD;
#pragma unroll
      for (int jd = 0; jd < 4; ++jd)
        o[base + jd * 16 + llo] = (bf16)(oacc[i][jd][r] * inv);
    }
  }
}

// ---------------------------------------------------------------------------
// Workspace layout (<= 64 MiB used):
//   [0, 16M)   qw [b,h,s,d] bf16   (later woT @0..2M after attn)
//   [16M,32M)  kw;  [32M,48M) vw [b,h,d,s]
//   [48M,64M)  phase1-2: wqkvT (6M) + cosT/sinT; phase3-4: ow bf16 (16M)
// d_out (33.5 MB f32) doubles as xb scratch (16.8 MB bf16) in phases 1-2.
// ---------------------------------------------------------------------------
extern "C" void kernel_launch(void* const* d_in, const int* in_sizes, int n_in,
                              void* d_out, int out_size, void* d_ws, size_t ws_size,
                              hipStream_t stream) {
  const float* x_raw = (const float*)d_in[0];
  const float* wqkv_raw = (const float*)d_in[1];
  const float* bqkv = (const float*)d_in[2];
  const float* wo_raw = (const float*)d_in[3];
  const float* bo = (const float*)d_in[4];
  float* out = (float*)d_out;

  char* ws = (char*)d_ws;
  bf16* qw = (bf16*)(ws);                       // 16 MiB
  bf16* kw = (bf16*)(ws + 16777216);            // 16 MiB
  bf16* vw = (bf16*)(ws + 33554432);            // 16 MiB
  bf16* wqkvT = (bf16*)(ws + 50331648);         // 6 MiB (phase 1-2)
  float* cosT = (float*)(ws + 56623104);        // 256 KiB (phase 1-2)
  float* sinT = (float*)(ws + 56885248);        // 256 KiB (phase 1-2)
  bf16* ow = (bf16*)(ws + 50331648);            // 16 MiB (phase 3-4, overlays above)
  bf16* woT = (bf16*)(ws);                      // 2 MiB (phase 3.5-4, overlays qw)
  bf16* xb = (bf16*)d_out;                      // 16.8 MiB scratch in d_out (phase 1-2)

  static bool attr_set = false;
  if (!attr_set) {
    (void)hipFuncSetAttribute((const void*)qkv8_kernel,
                              hipFuncAttributeMaxDynamicSharedMemorySize, 163840);
    (void)hipFuncSetAttribute((const void*)outproj8_kernel,
                              hipFuncAttributeMaxDynamicSharedMemorySize, 163840);
    attr_set = true;
  }

  rope_table<<<256, 256, 0, stream>>>(cosT, sinT);
  convert_bf16<<<(BATCH * SEQ * EMB / 4 + 255) / 256, 256, 0, stream>>>(
      x_raw, xb, BATCH * SEQ * EMB / 4);
  transpose_f32_bf16<<<dim3(F3 / 32, EMB / 32), 256, 0, stream>>>(wqkv_raw, wqkvT, EMB, F3);

  qkv8_kernel<<<dim3((BATCH * SEQ / 256) * (F3 / 256)), 512, 163840, stream>>>(
      xb, wqkvT, bqkv, qw, kw, vw, cosT, sinT);
  attn_kernel<<<dim3(BATCH * NH * (SEQ / 256)), 512, 0, stream>>>(qw, kw, vw, ow);

  transpose_f32_bf16<<<dim3(EMB / 32, EMB / 32), 256, 0, stream>>>(wo_raw, woT, EMB, EMB);
  outproj8_kernel<<<dim3((BATCH * SEQ / 256) * (EMB / 256)), 512, 163840, stream>>>(
      ow, woT, bo, out);
}

// Round 2
// 289.821 us; speedup vs baseline: 1.0029x; 1.0029x over previous
//
#include <hip/hip_runtime.h>
#include <stdint.h>
#include <stddef.h>

typedef __bf16 bf16;
typedef __attribute__((ext_vector_type(8))) __bf16 bf16x8;
typedef __attribute__((ext_vector_type(4))) __bf16 bf16x4;
typedef __attribute__((ext_vector_type(4))) float f32x4;
typedef __attribute__((ext_vector_type(16))) float f32x16;
typedef __attribute__((ext_vector_type(4))) float float4v;
typedef __attribute__((ext_vector_type(4))) uint32_t u32x4;

#define BATCH 4
#define SEQ   2048
#define EMB   1024
#define NH    16
#define HD    64
#define F3    3072   // 3*EMB

#define MFMA16(a, b, c) __builtin_amdgcn_mfma_f32_16x16x32_bf16((a), (b), (c), 0, 0, 0)
#define MFMA32(a, b, c) __builtin_amdgcn_mfma_f32_32x32x16_bf16((a), (b), (c), 0, 0, 0)

// async global->LDS, 16B per lane. lds ptr must be wave-uniform; lane i lands at l + i*16B.
__device__ __forceinline__ void gload_lds16(const bf16* g, bf16* l) {
  __builtin_amdgcn_global_load_lds(
      (const __attribute__((address_space(1))) uint32_t*)g,
      (__attribute__((address_space(3))) uint32_t*)l, 16, 0, 0);
}

__device__ __forceinline__ int mod10(int x) { return x >= 10 ? x - 10 : x; }  // x < 20

// ---------------------------------------------------------------------------
// RoPE table: cos/sin[pos][d1] for pos<2048, d1<32, f32 (ref keeps f32).
// ---------------------------------------------------------------------------
__global__ __launch_bounds__(256) void rope_table(float* __restrict__ cosT,
                                                  float* __restrict__ sinT) {
  int idx = blockIdx.x * 256 + threadIdx.x;   // 65536
  int pos = idx >> 5, d1 = idx & 31;
  float inv = powf(10000.0f, -(float)(2 * d1) / 64.0f);
  float th = (float)pos * inv;
  cosT[idx] = cosf(th);
  sinT[idx] = sinf(th);
}

// ---------------------------------------------------------------------------
// Convert f32 -> bf16. n4 = count/4.
// ---------------------------------------------------------------------------
__global__ __launch_bounds__(256) void convert_bf16(const float* __restrict__ src,
                                                    bf16* __restrict__ dst, int n4) {
  int i = blockIdx.x * 256 + threadIdx.x;
  if (i >= n4) return;
  float4v v = ((const float4v*)src)[i];
  bf16x4 o;
#pragma unroll
  for (int k = 0; k < 4; ++k) o[k] = (bf16)v[k];
  ((bf16x4*)dst)[i] = o;
}

// ---------------------------------------------------------------------------
// Transpose + convert: in [R][C] f32 -> out [C][R] bf16.
// ---------------------------------------------------------------------------
__global__ __launch_bounds__(256) void transpose_f32_bf16(const float* __restrict__ in,
                                                          bf16* __restrict__ out,
                                                          int R, int C) {
  __shared__ bf16 tile[32][33];
  const int tx = threadIdx.x & 31;
  const int ty = threadIdx.x >> 5;  // 0..7
  const int c0 = blockIdx.x * 32, r0 = blockIdx.y * 32;
#pragma unroll
  for (int kk = 0; kk < 4; ++kk) {
    int r = ty + kk * 8;
    tile[r][tx] = (bf16)in[(size_t)(r0 + r) * C + c0 + tx];
  }
  __syncthreads();
#pragma unroll
  for (int kk = 0; kk < 4; ++kk) {
    int r = ty + kk * 8;
    out[(size_t)(c0 + r) * R + r0 + tx] = tile[tx][r];
  }
}

// ---------------------------------------------------------------------------
// 256x256 / BK=64 8-phase MFMA GEMM core (unchanged from round 0).
// ---------------------------------------------------------------------------
__device__ __forceinline__ void gemm256_core(bf16* lds,
                                             const bf16* __restrict__ Abase,
                                             const bf16* __restrict__ Bbase,
                                             f32x4 (&acc)[8][4]) {
  const int tid = threadIdx.x;
  const int w = tid >> 6, lane = tid & 63;
  const int lhi = lane >> 4, llo = lane & 15, l7 = llo & 7;
  const int wr = w >> 2, wc = w & 3;          // 2M x 4N wave grid
  const int srow = lane >> 3;                 // staging row within 8-row chunk
  const int sk16 = (lane & 7) ^ srow;         // pre-swizzled global 16B granule
  const size_t g_lane = (size_t)(w * 16 + srow) * EMB + sk16 * 8;
  bf16* ldsw = lds + w * 1024;                // wave chunk base within a slot

  const int ka0 = (lhi * 8) ^ (l7 << 3);
  const int ka1 = (32 + lhi * 8) ^ (l7 << 3);
  const int arow = llo * 64;                        // A frag row base (elems)
  const int brow = ((wc & 1) * 64 + llo) * 64;      // B frag row base (elems)

#pragma unroll
  for (int i = 0; i < 8; ++i)
#pragma unroll
    for (int j = 0; j < 4; ++j) acc[i][j] = (f32x4){0.f, 0.f, 0.f, 0.f};

#define STAGE(baseptr, slot)                              \
  do {                                                    \
    const bf16* _b = (baseptr);                           \
    bf16* _l = ldsw + (slot) * 8192;                      \
    gload_lds16(_b + g_lane, _l);                         \
    gload_lds16(_b + g_lane + 8 * EMB, _l + 512);         \
  } while (0)

  STAGE(Abase, 0);
  STAGE(Abase + 128 * EMB, 1);
  STAGE(Bbase, 2);
  STAGE(Bbase + 128 * EMB, 3);
  STAGE(Abase + 64, 4);
  STAGE(Abase + 128 * EMB + 64, 5);
  asm volatile("s_waitcnt vmcnt(4)" ::: "memory");
  __builtin_amdgcn_s_barrier();

  int rs = 0;  // (4t) % 10
#pragma unroll 1
  for (int t = 0; t < 16; ++t) {
    const bf16* ldsA = lds + mod10(rs + wr) * 8192 + arow;
    const bf16* ldsB = lds + mod10(rs + 2 + (wc >> 1)) * 8192 + brow;
    const int k1 = (t + 1) * 64;
    const int k2 = (t + 2) * 64;
    bf16x8 a[4][2], b0[2][2], b1[2][2];

    // ---- phase 0
#pragma unroll
    for (int i = 0; i < 4; ++i) {
      a[i][0] = *(const bf16x8*)(ldsA + i * 1024 + ka0);
      a[i][1] = *(const bf16x8*)(ldsA + i * 1024 + ka1);
    }
#pragma unroll
    for (int j = 0; j < 2; ++j) {
      b0[j][0] = *(const bf16x8*)(ldsB + j * 1024 + ka0);
      b0[j][1] = *(const bf16x8*)(ldsB + j * 1024 + ka1);
    }
    if (t < 15) STAGE(Bbase + k1, mod10(rs + 6));
    __builtin_amdgcn_s_barrier();
    asm volatile("s_waitcnt lgkmcnt(0)" ::: "memory");
    __builtin_amdgcn_sched_barrier(0);
    __builtin_amdgcn_s_setprio(1);
#pragma unroll
    for (int i = 0; i < 4; ++i)
#pragma unroll
      for (int j = 0; j < 2; ++j) {
        acc[i][j] = MFMA16(a[i][0], b0[j][0], acc[i][j]);
        acc[i][j] = MFMA16(a[i][1], b0[j][1], acc[i][j]);
      }
    __builtin_amdgcn_s_setprio(0);
    __builtin_amdgcn_s_barrier();

    // ---- phase 1
#pragma unroll
    for (int j = 0; j < 2; ++j) {
      b1[j][0] = *(const bf16x8*)(ldsB + 2048 + j * 1024 + ka0);
      b1[j][1] = *(const bf16x8*)(ldsB + 2048 + j * 1024 + ka1);
    }
    if (t < 15) STAGE(Bbase + 128 * EMB + k1, mod10(rs + 7));
    __builtin_amdgcn_s_barrier();
    asm volatile("s_waitcnt lgkmcnt(0)" ::: "memory");
    __builtin_amdgcn_sched_barrier(0);
    __builtin_amdgcn_s_setprio(1);
#pragma unroll
    for (int i = 0; i < 4; ++i)
#pragma unroll
      for (int j = 0; j < 2; ++j) {
        acc[i][2 + j] = MFMA16(a[i][0], b1[j][0], acc[i][2 + j]);
        acc[i][2 + j] = MFMA16(a[i][1], b1[j][1], acc[i][2 + j]);
      }
    __builtin_amdgcn_s_setprio(0);
    __builtin_amdgcn_s_barrier();

    // ---- phase 2
#pragma unroll
    for (int i = 0; i < 4; ++i) {
      a[i][0] = *(const bf16x8*)(ldsA + 4096 + i * 1024 + ka0);
      a[i][1] = *(const bf16x8*)(ldsA + 4096 + i * 1024 + ka1);
    }
    if (t < 14) STAGE(Abase + k2, mod10(rs + 8));
    __builtin_amdgcn_s_barrier();
    asm volatile("s_waitcnt lgkmcnt(0)" ::: "memory");
    __builtin_amdgcn_sched_barrier(0);
    __builtin_amdgcn_s_setprio(1);
#pragma unroll
    for (int i = 0; i < 4; ++i)
#pragma unroll
      for (int j = 0; j < 2; ++j) {
        acc[4 + i][2 + j] = MFMA16(a[i][0], b1[j][0], acc[4 + i][2 + j]);
        acc[4 + i][2 + j] = MFMA16(a[i][1], b1[j][1], acc[4 + i][2 + j]);
      }
    __builtin_amdgcn_s_setprio(0);
    __builtin_amdgcn_s_barrier();

    // ---- phase 3
    if (t < 14) STAGE(Abase + 128 * EMB + k2, mod10(rs + 9));
    __builtin_amdgcn_s_barrier();
    asm volatile("s_waitcnt lgkmcnt(0)" ::: "memory");
    __builtin_amdgcn_sched_barrier(0);
    __builtin_amdgcn_s_setprio(1);
#pragma unroll
    for (int i = 0; i < 4; ++i)
#pragma unroll
      for (int j = 0; j < 2; ++j) {
        acc[4 + i][j] = MFMA16(a[i][0], b0[j][0], acc[4 + i][j]);
        acc[4 + i][j] = MFMA16(a[i][1], b0[j][1], acc[4 + i][j]);
      }
    __builtin_amdgcn_s_setprio(0);
    if (t < 14) {
      asm volatile("s_waitcnt vmcnt(4)" ::: "memory");
    } else if (t == 14) {
      asm volatile("s_waitcnt vmcnt(0)" ::: "memory");
    }
    if (t < 15) __builtin_amdgcn_s_barrier();

    rs += 4;
    if (rs >= 10) rs -= 10;
  }
#undef STAGE
}

// ---------------------------------------------------------------------------
// QKV GEMM (8-phase 256^2 core) + bias + RoPE + scatter epilogue.
// ---------------------------------------------------------------------------
__global__ __launch_bounds__(512, 2) void qkv8_kernel(
    const bf16* __restrict__ x, const bf16* __restrict__ wT,
    const float* __restrict__ bias, bf16* __restrict__ qo, bf16* __restrict__ ko,
    bf16* __restrict__ vo, const float* __restrict__ cosT,
    const float* __restrict__ sinT) {
  extern __shared__ __align__(16) bf16 ldsb[];
  const int orig = blockIdx.x;
  const int wg = (orig & 7) * 48 + (orig >> 3);   // 48 contiguous wgs per XCD
  const int bx = wg % 12, by = wg / 12;
  const int row_a0 = by * 256, row_b0 = bx * 256;

  f32x4 acc[8][4];
  gemm256_core(ldsb, x + (size_t)row_a0 * EMB, wT + (size_t)row_b0 * EMB, acc);

  const int tid = threadIdx.x;
  const int w = tid >> 6, lane = tid & 63;
  const int lhi = lane >> 4, llo = lane & 15;
  const int wr = w >> 2, wc = w & 3;

  const int f0 = row_b0 + wc * 64;      // wave col base, 64-aligned
  const int part = f0 >> 10;            // 0=Q 1=K 2=V
  const int hh = (f0 & 1023) >> 6;      // head
  const int m_base = row_a0 + wr * 128;

  float bvals[4];
#pragma unroll
  for (int j = 0; j < 4; ++j) bvals[j] = bias[f0 + j * 16 + llo];

  if (part == 2) {
#pragma unroll
    for (int mi = 0; mi < 8; ++mi) {
      int m0 = m_base + mi * 16 + lhi * 4;
      int bb = m0 >> 11, pos0 = m0 & 2047;
#pragma unroll
      for (int j = 0; j < 4; ++j) {
        int dd = j * 16 + llo;
        bf16x4 pk;
#pragma unroll
        for (int r = 0; r < 4; ++r) pk[r] = (bf16)(acc[mi][j][r] + bvals[j]);
        *(bf16x4*)(vo + ((size_t)(bb * NH + hh) * HD + dd) * SEQ + pos0) = pk;
      }
    }
  } else {
    bf16* dst = (part == 0) ? qo : ko;
    const float qs = (part == 0) ? 0.125f : 1.0f;  // fold 1/sqrt(64) into Q (exact pow2)
#pragma unroll
    for (int mi = 0; mi < 8; ++mi) {
#pragma unroll
      for (int r = 0; r < 4; ++r) {
        int m = m_base + mi * 16 + lhi * 4 + r;
        int bb = m >> 11, pos = m & 2047;
        size_t base = ((size_t)(bb * NH + hh) * SEQ + pos) * HD;
#pragma unroll
        for (int j = 0; j < 2; ++j) {
          int d1 = j * 16 + llo;
          float x1 = acc[mi][j][r] + bvals[j];
          float x2 = acc[mi][j + 2][r] + bvals[j + 2];
          float cth = cosT[pos * 32 + d1];
          float sth = sinT[pos * 32 + d1];
          dst[base + d1] = (bf16)((x1 * cth - x2 * sth) * qs);
          dst[base + d1 + 32] = (bf16)((x2 * cth + x1 * sth) * qs);
        }
      }
    }
  }
}

// ---------------------------------------------------------------------------
// Output projection on the same 8-phase core.
// ---------------------------------------------------------------------------
__global__ __launch_bounds__(512, 2) void outproj8_kernel(
    const bf16* __restrict__ a_in, const bf16* __restrict__ wT,
    const float* __restrict__ bo, float* __restrict__ out) {
  extern __shared__ __align__(16) bf16 ldsb[];
  const int orig = blockIdx.x;
  const int wg = (orig & 7) * 16 + (orig >> 3);   // 128 % 8 == 0
  const int bx = wg % 4, by = wg / 4;
  const int row_a0 = by * 256, row_b0 = bx * 256;

  f32x4 acc[8][4];
  gemm256_core(ldsb, a_in + (size_t)row_a0 * EMB, wT + (size_t)row_b0 * EMB, acc);

  const int tid = threadIdx.x;
  const int w = tid >> 6, lane = tid & 63;
  const int lhi = lane >> 4, llo = lane & 15;
  const int wr = w >> 2, wc = w & 3;

  const int col0 = row_b0 + wc * 64;
  const int m_base = row_a0 + wr * 128;
  float bvals[4];
#pragma unroll
  for (int j = 0; j < 4; ++j) bvals[j] = bo[col0 + j * 16 + llo];
#pragma unroll
  for (int mi = 0; mi < 8; ++mi) {
#pragma unroll
    for (int r = 0; r < 4; ++r) {
      int m = m_base + mi * 16 + lhi * 4 + r;
#pragma unroll
      for (int j = 0; j < 4; ++j)
        out[(size_t)m * EMB + col0 + j * 16 + llo] = acc[mi][j][r] + bvals[j];
    }
  }
}

// ---------------------------------------------------------------------------
// Flash attention v5: 8 waves x 32 q-rows, 32x32x16 MFMA, swapped QK^T
// (S^T = K*Q^T -> each lane owns one q-row's scores), in-register softmax,
// P redistributed to PV A-frags via v_cvt_pk_bf16_f32 + v_permlane32_swap_b32
// (T12) -- P never touches LDS. Q in registers. K / V^T double-buffered in
// LDS (32 KB), XOR-swizzled (granule ^= row&7), gload_lds16 staging with
// pre-swizzled global source (same involution as staging write).
// Frag layouts (32x32x16_bf16): A[row=lane&31][k=(lane>>5)*8+j],
// B[k=(lane>>5)*8+j][col=lane&31], C/D col=lane&31,
// row=(reg&3)+8*(reg>>2)+4*(lane>>5)  [m74/m101-verified].
// ---------------------------------------------------------------------------
__global__ __launch_bounds__(512, 2) void attn32_kernel(const bf16* __restrict__ q,
                                                        const bf16* __restrict__ k,
                                                        const bf16* __restrict__ vT,
                                                        bf16* __restrict__ o) {
  __shared__ __align__(16) bf16 smem[16384];  // K dbuf 2x4096, V dbuf 2x4096 elems

  const int tid = threadIdx.x, w = tid >> 6, lane = tid & 63;
  const int l31 = lane & 31, hi = lane >> 5;
  const int bidx = blockIdx.x;
  const int vblk = (bidx & 7) * 64 + (bidx >> 3);  // XCD-contiguous remap (512 blocks)
  const int qt = vblk & 7, bh = vblk >> 3;         // 8 q-tiles of 256, bh in [0,64)
  const bf16* qbase = q + (size_t)bh * SEQ * HD + qt * 256 * HD;
  const bf16* kbase = k + (size_t)bh * SEQ * HD;
  const bf16* vbase = vT + (size_t)bh * HD * SEQ;

  const int rowc = lane >> 3;                     // row within 8-row chunk
  const int sw8 = (lane & 7) ^ rowc;              // staging XOR swizzle (16B granules)

  // Q -> registers: B-frag qf[c] = Q[q=l31][c*16 + hi*8 + j], rows w*32+l31
  bf16x8 qf[4];
  {
    const bf16* qrow = qbase + (size_t)(w * 32 + l31) * HD;
#pragma unroll
    for (int c = 0; c < 4; ++c) qf[c] = *(const bf16x8*)(qrow + c * 16 + hi * 8);
  }

  // stage tile 0: waves 0-3 K (64tok x 64d), waves 4-7 V^T (64d x 64tok)
  if (w < 4) {
#pragma unroll
    for (int c = 0; c < 2; ++c) {
      int ch = w * 2 + c, row = ch * 8 + rowc;
      gload_lds16(kbase + (size_t)row * HD + sw8 * 8, &smem[ch * 512]);
    }
  } else {
#pragma unroll
    for (int c = 0; c < 2; ++c) {
      int ch = (w - 4) * 2 + c, row = ch * 8 + rowc;
      gload_lds16(vbase + (size_t)row * SEQ + sw8 * 8, &smem[8192 + ch * 512]);
    }
  }
  __syncthreads();

  float rsum = 0.f;
  f32x16 oacc[2];
#pragma unroll
  for (int r = 0; r < 16; ++r) { oacc[0][r] = 0.f; oacc[1][r] = 0.f; }

  const int swz = (l31 & 7);  // row&7 for frag reads (rows = tile_base + l31)

  for (int kb = 0; kb < 32; ++kb) {
    bf16* Kc = smem + (kb & 1) * 4096;
    bf16* Vc = smem + 8192 + (kb & 1) * 4096;
    // prefetch next tile into alt buffers
    if (kb < 31) {
      int kpos = (kb + 1) * 64;
      if (w < 4) {
        bf16* Kn = smem + ((kb + 1) & 1) * 4096;
#pragma unroll
        for (int c = 0; c < 2; ++c) {
          int ch = w * 2 + c, row = ch * 8 + rowc;
          gload_lds16(kbase + (size_t)(kpos + row) * HD + sw8 * 8, &Kn[ch * 512]);
        }
      } else {
        bf16* Vn = smem + 8192 + ((kb + 1) & 1) * 4096;
#pragma unroll
        for (int c = 0; c < 2; ++c) {
          int ch = (w - 4) * 2 + c, row = ch * 8 + rowc;
          gload_lds16(vbase + (size_t)row * SEQ + kpos + sw8 * 8, &Vn[ch * 512]);
        }
      }
    }

    // ---- QK^T: S^T[tok][q], token tiles tt=0,1; k-chunks c of 16 dims
    f32x16 st0, st1;
#pragma unroll
    for (int r = 0; r < 16; ++r) { st0[r] = 0.f; st1[r] = 0.f; }
    __builtin_amdgcn_s_setprio(1);
#pragma unroll
    for (int c = 0; c < 4; ++c) {
      bf16x8 kf0 = *(const bf16x8*)&Kc[l31 * 64 + (((c * 2 + hi) ^ swz) * 8)];
      bf16x8 kf1 = *(const bf16x8*)&Kc[(32 + l31) * 64 + (((c * 2 + hi) ^ swz) * 8)];
      st0 = MFMA32(kf0, qf[c], st0);
      st1 = MFMA32(kf1, qf[c], st1);
    }
    __builtin_amdgcn_s_setprio(0);

    // ---- softmax: p = exp(s) in place (Q prescaled 1/8); tree-sum rsum
#pragma unroll
    for (int r = 0; r < 16; ++r) {
      st0[r] = __expf(st0[r]);
      st1[r] = __expf(st1[r]);
    }
    {
      float a0 = 0.f, a1 = 0.f, a2 = 0.f, a3 = 0.f;
#pragma unroll
      for (int r = 0; r < 16; r += 4) {
        a0 += st0[r];     a1 += st0[r + 1];
        a2 += st0[r + 2]; a3 += st0[r + 3];
      }
#pragma unroll
      for (int r = 0; r < 16; r += 4) {
        a0 += st1[r];     a1 += st1[r + 1];
        a2 += st1[r + 2]; a3 += st1[r + 3];
      }
      rsum += (a0 + a1) + (a2 + a3);
    }

    // ---- P -> PV A-frags (T12): per (tt,c1): 4 cvt_pk + 2 permlane32_swap.
    // Regs c1*8+0..3 (G0): hi0 -> tok c1*16+0..3, hi1 -> +4..7.
    // Regs c1*8+4..7 (G1): hi0 -> tok c1*16+8..11, hi1 -> +12..15.
    // swap(A,B) exchanges A[lanes32-63] <-> B[lanes0-31]:
    //   A := [hi0: own G0 | hi1: partner G1]  = PA tokens j0..3
    //   B := [hi0: partner G0 | hi1: own G1]  = PA tokens j4..7
    bf16x8 pa[4];
#pragma unroll
    for (int tt = 0; tt < 2; ++tt) {
#pragma unroll
      for (int c1 = 0; c1 < 2; ++c1) {
        float s0 = tt ? st1[c1 * 8 + 0] : st0[c1 * 8 + 0];
        float s1 = tt ? st1[c1 * 8 + 1] : st0[c1 * 8 + 1];
        float s2 = tt ? st1[c1 * 8 + 2] : st0[c1 * 8 + 2];
        float s3 = tt ? st1[c1 * 8 + 3] : st0[c1 * 8 + 3];
        float s4 = tt ? st1[c1 * 8 + 4] : st0[c1 * 8 + 4];
        float s5 = tt ? st1[c1 * 8 + 5] : st0[c1 * 8 + 5];
        float s6 = tt ? st1[c1 * 8 + 6] : st0[c1 * 8 + 6];
        float s7 = tt ? st1[c1 * 8 + 7] : st0[c1 * 8 + 7];
        uint32_t a0, a1, b0, b1;
        asm("v_cvt_pk_bf16_f32 %0, %1, %2" : "=v"(a0) : "v"(s0), "v"(s1));
        asm("v_cvt_pk_bf16_f32 %0, %1, %2" : "=v"(a1) : "v"(s2), "v"(s3));
        asm("v_cvt_pk_bf16_f32 %0, %1, %2" : "=v"(b0) : "v"(s4), "v"(s5));
        asm("v_cvt_pk_bf16_f32 %0, %1, %2" : "=v"(b1) : "v"(s6), "v"(s7));
        asm("v_permlane32_swap_b32 %0, %1" : "+v"(a0), "+v"(b0));
        asm("v_permlane32_swap_b32 %0, %1" : "+v"(a1), "+v"(b1));
        u32x4 uv = {a0, a1, b0, b1};
        pa[tt * 2 + c1] = __builtin_bit_cast(bf16x8, uv);
      }
    }

    // ---- O += P V : A=pa[c] (tokens c*16..+15), B=V^T rows d=jt*32+l31
    __builtin_amdgcn_s_setprio(1);
#pragma unroll
    for (int c = 0; c < 4; ++c) {
      bf16x8 v0 = *(const bf16x8*)&Vc[l31 * 64 + (((c * 2 + hi) ^ swz) * 8)];
      bf16x8 v1 = *(const bf16x8*)&Vc[(32 + l31) * 64 + (((c * 2 + hi) ^ swz) * 8)];
      oacc[0] = MFMA32(pa[c], v0, oacc[0]);
      oacc[1] = MFMA32(pa[c], v1, oacc[1]);
    }
    __builtin_amdgcn_s_setprio(0);

    __syncthreads();  // prefetch landed + guards buffer reuse
  }

  // epilogue: rsum(q=l31) split across lane halves -> combine; redistribute
  // to C-layout row owners via shfl; normalize and write.
  rsum += __shfl_xor(rsum, 32);
  const int bb = bh >> 4, hh = bh & 15;
#pragma unroll
  for (int r = 0; r < 16; ++r) {
    int qrow = (r & 3) + 8 * (r >> 2) + 4 * hi;
    float inv = 1.0f / __shfl(rsum, qrow);
    int pos = qt * 256 + w * 32 + qrow;
    size_t base = ((size_t)bb * SEQ + pos) * EMB + hh * HD;
    o[base + l31] = (bf16)(oacc[0][r] * inv);
    o[base + 32 + l31] = (bf16)(oacc[1][r] * inv);
  }
}

// ---------------------------------------------------------------------------
// Workspace layout (<= 64 MiB used):
//   [0, 16M)   qw [b,h,s,d] bf16   (later woT @0..2M after attn)
//   [16M,32M)  kw;  [32M,48M) vw [b,h,d,s]
//   [48M,64M)  phase1-2: wqkvT (6M) + cosT/sinT; phase3-4: ow bf16 (16M)
// d_out (33.5 MB f32) doubles as xb scratch (16.8 MB bf16) in phases 1-2.
// ---------------------------------------------------------------------------
extern "C" void kernel_launch(void* const* d_in, const int* in_sizes, int n_in,
                              void* d_out, int out_size, void* d_ws, size_t ws_size,
                              hipStream_t stream) {
  const float* x_raw = (const float*)d_in[0];
  const float* wqkv_raw = (const float*)d_in[1];
  const float* bqkv = (const float*)d_in[2];
  const float* wo_raw = (const float*)d_in[3];
  const float* bo = (const float*)d_in[4];
  float* out = (float*)d_out;

  char* ws = (char*)d_ws;
  bf16* qw = (bf16*)(ws);                       // 16 MiB
  bf16* kw = (bf16*)(ws + 16777216);            // 16 MiB
  bf16* vw = (bf16*)(ws + 33554432);            // 16 MiB
  bf16* wqkvT = (bf16*)(ws + 50331648);         // 6 MiB (phase 1-2)
  float* cosT = (float*)(ws + 56623104);        // 256 KiB (phase 1-2)
  float* sinT = (float*)(ws + 56885248);        // 256 KiB (phase 1-2)
  bf16* ow = (bf16*)(ws + 50331648);            // 16 MiB (phase 3-4, overlays above)
  bf16* woT = (bf16*)(ws);                      // 2 MiB (phase 3.5-4, overlays qw)
  bf16* xb = (bf16*)d_out;                      // 16.8 MiB scratch in d_out (phase 1-2)

  static bool attr_set = false;
  if (!attr_set) {
    (void)hipFuncSetAttribute((const void*)qkv8_kernel,
                              hipFuncAttributeMaxDynamicSharedMemorySize, 163840);
    (void)hipFuncSetAttribute((const void*)outproj8_kernel,
                              hipFuncAttributeMaxDynamicSharedMemorySize, 163840);
    attr_set = true;
  }

  rope_table<<<256, 256, 0, stream>>>(cosT, sinT);
  convert_bf16<<<(BATCH * SEQ * EMB / 4 + 255) / 256, 256, 0, stream>>>(
      x_raw, xb, BATCH * SEQ * EMB / 4);
  transpose_f32_bf16<<<dim3(F3 / 32, EMB / 32), 256, 0, stream>>>(wqkv_raw, wqkvT, EMB, F3);

  qkv8_kernel<<<dim3((BATCH * SEQ / 256) * (F3 / 256)), 512, 163840, stream>>>(
      xb, wqkvT, bqkv, qw, kw, vw, cosT, sinT);
  attn32_kernel<<<dim3(BATCH * NH * (SEQ / 256)), 512, 0, stream>>>(qw, kw, vw, ow);

  transpose_f32_bf16<<<dim3(EMB / 32, EMB / 32), 256, 0, stream>>>(wo_raw, woT, EMB, EMB);
  outproj8_kernel<<<dim3((BATCH * SEQ / 256) * (EMB / 256)), 512, 163840, stream>>>(
      ow, woT, bo, out);
}

// Round 4
// 287.212 us; speedup vs baseline: 1.0120x; 1.0091x over previous
//
#include <hip/hip_runtime.h>
#include <stdint.h>
#include <stddef.h>

typedef __bf16 bf16;
typedef __attribute__((ext_vector_type(8))) __bf16 bf16x8;
typedef __attribute__((ext_vector_type(4))) __bf16 bf16x4;
typedef __attribute__((ext_vector_type(4))) float f32x4;
typedef __attribute__((ext_vector_type(16))) float f32x16;
typedef __attribute__((ext_vector_type(4))) float float4v;
typedef __attribute__((ext_vector_type(4))) uint32_t u32x4;

#define BATCH 4
#define SEQ   2048
#define EMB   1024
#define NH    16
#define HD    64
#define F3    3072   // 3*EMB

#define MFMA16(a, b, c) __builtin_amdgcn_mfma_f32_16x16x32_bf16((a), (b), (c), 0, 0, 0)
#define MFMA32(a, b, c) __builtin_amdgcn_mfma_f32_32x32x16_bf16((a), (b), (c), 0, 0, 0)

// async global->LDS, 16B per lane. lds ptr must be wave-uniform; lane i lands at l + i*16B.
__device__ __forceinline__ void gload_lds16(const bf16* g, bf16* l) {
  __builtin_amdgcn_global_load_lds(
      (const __attribute__((address_space(1))) uint32_t*)g,
      (__attribute__((address_space(3))) uint32_t*)l, 16, 0, 0);
}

__device__ __forceinline__ int mod10(int x) { return x >= 10 ? x - 10 : x; }  // x < 20

// ---------------------------------------------------------------------------
// 32x32 tile transpose+convert helper (shared by prep_kernel and the wo pass).
// ---------------------------------------------------------------------------
__device__ __forceinline__ void transpose_tile32(const float* __restrict__ in,
                                                 bf16* __restrict__ out,
                                                 int R, int C, int bx, int by) {
  __shared__ bf16 tile[32][33];
  const int tx = threadIdx.x & 31;
  const int ty = threadIdx.x >> 5;  // 0..7
  const int c0 = bx * 32, r0 = by * 32;
#pragma unroll
  for (int kk = 0; kk < 4; ++kk) {
    int r = ty + kk * 8;
    tile[r][tx] = (bf16)in[(size_t)(r0 + r) * C + c0 + tx];
  }
  __syncthreads();
#pragma unroll
  for (int kk = 0; kk < 4; ++kk) {
    int r = ty + kk * 8;
    out[(size_t)(c0 + r) * R + r0 + tx] = tile[tx][r];
  }
}

// ---------------------------------------------------------------------------
// Fused prep: region-dispatched by blockIdx (7->5 total launches).
//   [0, 8192)        : convert x f32 -> bf16 (2M float4 groups, exact fit)
//   [8192, 11264)    : transpose wqkv [1024][3072] f32 -> wqkvT [3072][1024] bf16
//   [11264, 11520)   : RoPE cos/sin table (2048 pos x 32 d1, f32)
// ---------------------------------------------------------------------------
__global__ __launch_bounds__(256) void prep_kernel(const float* __restrict__ x_raw,
                                                   bf16* __restrict__ xb,
                                                   const float* __restrict__ wqkv_raw,
                                                   bf16* __restrict__ wqkvT,
                                                   float* __restrict__ cosT,
                                                   float* __restrict__ sinT) {
  const int blk = blockIdx.x;
  if (blk < 8192) {
    int i = blk * 256 + threadIdx.x;   // 8192*256 == BATCH*SEQ*EMB/4 exactly
    float4v v = ((const float4v*)x_raw)[i];
    bf16x4 o;
#pragma unroll
    for (int k = 0; k < 4; ++k) o[k] = (bf16)v[k];
    ((bf16x4*)xb)[i] = o;
  } else if (blk < 11264) {
    int idx = blk - 8192;              // 3072 tiles: 96 col-tiles x 32 row-tiles
    transpose_tile32(wqkv_raw, wqkvT, EMB, F3, idx % 96, idx / 96);
  } else {
    int idx = (blk - 11264) * 256 + threadIdx.x;   // 65536
    int pos = idx >> 5, d1 = idx & 31;
    float inv = powf(10000.0f, -(float)(2 * d1) / 64.0f);
    float th = (float)pos * inv;
    cosT[idx] = cosf(th);
    sinT[idx] = sinf(th);
  }
}

// ---------------------------------------------------------------------------
// Standalone transpose (wo only; must run after attn frees the woT region).
// ---------------------------------------------------------------------------
__global__ __launch_bounds__(256) void transpose_f32_bf16(const float* __restrict__ in,
                                                          bf16* __restrict__ out,
                                                          int R, int C) {
  transpose_tile32(in, out, R, C, blockIdx.x, blockIdx.y);
}

// ---------------------------------------------------------------------------
// 256x256 / BK=64 8-phase MFMA GEMM core (unchanged from round 1).
// ---------------------------------------------------------------------------
__device__ __forceinline__ void gemm256_core(bf16* lds,
                                             const bf16* __restrict__ Abase,
                                             const bf16* __restrict__ Bbase,
                                             f32x4 (&acc)[8][4]) {
  const int tid = threadIdx.x;
  const int w = tid >> 6, lane = tid & 63;
  const int lhi = lane >> 4, llo = lane & 15, l7 = llo & 7;
  const int wr = w >> 2, wc = w & 3;          // 2M x 4N wave grid
  const int srow = lane >> 3;                 // staging row within 8-row chunk
  const int sk16 = (lane & 7) ^ srow;         // pre-swizzled global 16B granule
  const size_t g_lane = (size_t)(w * 16 + srow) * EMB + sk16 * 8;
  bf16* ldsw = lds + w * 1024;                // wave chunk base within a slot

  const int ka0 = (lhi * 8) ^ (l7 << 3);
  const int ka1 = (32 + lhi * 8) ^ (l7 << 3);
  const int arow = llo * 64;                        // A frag row base (elems)
  const int brow = ((wc & 1) * 64 + llo) * 64;      // B frag row base (elems)

#pragma unroll
  for (int i = 0; i < 8; ++i)
#pragma unroll
    for (int j = 0; j < 4; ++j) acc[i][j] = (f32x4){0.f, 0.f, 0.f, 0.f};

#define STAGE(baseptr, slot)                              \
  do {                                                    \
    const bf16* _b = (baseptr);                           \
    bf16* _l = ldsw + (slot) * 8192;                      \
    gload_lds16(_b + g_lane, _l);                         \
    gload_lds16(_b + g_lane + 8 * EMB, _l + 512);         \
  } while (0)

  STAGE(Abase, 0);
  STAGE(Abase + 128 * EMB, 1);
  STAGE(Bbase, 2);
  STAGE(Bbase + 128 * EMB, 3);
  STAGE(Abase + 64, 4);
  STAGE(Abase + 128 * EMB + 64, 5);
  asm volatile("s_waitcnt vmcnt(4)" ::: "memory");
  __builtin_amdgcn_s_barrier();

  int rs = 0;  // (4t) % 10
#pragma unroll 1
  for (int t = 0; t < 16; ++t) {
    const bf16* ldsA = lds + mod10(rs + wr) * 8192 + arow;
    const bf16* ldsB = lds + mod10(rs + 2 + (wc >> 1)) * 8192 + brow;
    const int k1 = (t + 1) * 64;
    const int k2 = (t + 2) * 64;
    bf16x8 a[4][2], b0[2][2], b1[2][2];

    // ---- phase 0
#pragma unroll
    for (int i = 0; i < 4; ++i) {
      a[i][0] = *(const bf16x8*)(ldsA + i * 1024 + ka0);
      a[i][1] = *(const bf16x8*)(ldsA + i * 1024 + ka1);
    }
#pragma unroll
    for (int j = 0; j < 2; ++j) {
      b0[j][0] = *(const bf16x8*)(ldsB + j * 1024 + ka0);
      b0[j][1] = *(const bf16x8*)(ldsB + j * 1024 + ka1);
    }
    if (t < 15) STAGE(Bbase + k1, mod10(rs + 6));
    __builtin_amdgcn_s_barrier();
    asm volatile("s_waitcnt lgkmcnt(0)" ::: "memory");
    __builtin_amdgcn_sched_barrier(0);
    __builtin_amdgcn_s_setprio(1);
#pragma unroll
    for (int i = 0; i < 4; ++i)
#pragma unroll
      for (int j = 0; j < 2; ++j) {
        acc[i][j] = MFMA16(a[i][0], b0[j][0], acc[i][j]);
        acc[i][j] = MFMA16(a[i][1], b0[j][1], acc[i][j]);
      }
    __builtin_amdgcn_s_setprio(0);
    __builtin_amdgcn_s_barrier();

    // ---- phase 1
#pragma unroll
    for (int j = 0; j < 2; ++j) {
      b1[j][0] = *(const bf16x8*)(ldsB + 2048 + j * 1024 + ka0);
      b1[j][1] = *(const bf16x8*)(ldsB + 2048 + j * 1024 + ka1);
    }
    if (t < 15) STAGE(Bbase + 128 * EMB + k1, mod10(rs + 7));
    __builtin_amdgcn_s_barrier();
    asm volatile("s_waitcnt lgkmcnt(0)" ::: "memory");
    __builtin_amdgcn_sched_barrier(0);
    __builtin_amdgcn_s_setprio(1);
#pragma unroll
    for (int i = 0; i < 4; ++i)
#pragma unroll
      for (int j = 0; j < 2; ++j) {
        acc[i][2 + j] = MFMA16(a[i][0], b1[j][0], acc[i][2 + j]);
        acc[i][2 + j] = MFMA16(a[i][1], b1[j][1], acc[i][2 + j]);
      }
    __builtin_amdgcn_s_setprio(0);
    __builtin_amdgcn_s_barrier();

    // ---- phase 2
#pragma unroll
    for (int i = 0; i < 4; ++i) {
      a[i][0] = *(const bf16x8*)(ldsA + 4096 + i * 1024 + ka0);
      a[i][1] = *(const bf16x8*)(ldsA + 4096 + i * 1024 + ka1);
    }
    if (t < 14) STAGE(Abase + k2, mod10(rs + 8));
    __builtin_amdgcn_s_barrier();
    asm volatile("s_waitcnt lgkmcnt(0)" ::: "memory");
    __builtin_amdgcn_sched_barrier(0);
    __builtin_amdgcn_s_setprio(1);
#pragma unroll
    for (int i = 0; i < 4; ++i)
#pragma unroll
      for (int j = 0; j < 2; ++j) {
        acc[4 + i][2 + j] = MFMA16(a[i][0], b1[j][0], acc[4 + i][2 + j]);
        acc[4 + i][2 + j] = MFMA16(a[i][1], b1[j][1], acc[4 + i][2 + j]);
      }
    __builtin_amdgcn_s_setprio(0);
    __builtin_amdgcn_s_barrier();

    // ---- phase 3
    if (t < 14) STAGE(Abase + 128 * EMB + k2, mod10(rs + 9));
    __builtin_amdgcn_s_barrier();
    asm volatile("s_waitcnt lgkmcnt(0)" ::: "memory");
    __builtin_amdgcn_sched_barrier(0);
    __builtin_amdgcn_s_setprio(1);
#pragma unroll
    for (int i = 0; i < 4; ++i)
#pragma unroll
      for (int j = 0; j < 2; ++j) {
        acc[4 + i][j] = MFMA16(a[i][0], b0[j][0], acc[4 + i][j]);
        acc[4 + i][j] = MFMA16(a[i][1], b0[j][1], acc[4 + i][j]);
      }
    __builtin_amdgcn_s_setprio(0);
    if (t < 14) {
      asm volatile("s_waitcnt vmcnt(4)" ::: "memory");
    } else if (t == 14) {
      asm volatile("s_waitcnt vmcnt(0)" ::: "memory");
    }
    if (t < 15) __builtin_amdgcn_s_barrier();

    rs += 4;
    if (rs >= 10) rs -= 10;
  }
#undef STAGE
}

// ---------------------------------------------------------------------------
// QKV GEMM (8-phase 256^2 core) + bias + RoPE + scatter epilogue.
// ---------------------------------------------------------------------------
__global__ __launch_bounds__(512, 2) void qkv8_kernel(
    const bf16* __restrict__ x, const bf16* __restrict__ wT,
    const float* __restrict__ bias, bf16* __restrict__ qo, bf16* __restrict__ ko,
    bf16* __restrict__ vo, const float* __restrict__ cosT,
    const float* __restrict__ sinT) {
  extern __shared__ __align__(16) bf16 ldsb[];
  const int orig = blockIdx.x;
  const int wg = (orig & 7) * 48 + (orig >> 3);   // 48 contiguous wgs per XCD
  const int bx = wg % 12, by = wg / 12;
  const int row_a0 = by * 256, row_b0 = bx * 256;

  f32x4 acc[8][4];
  gemm256_core(ldsb, x + (size_t)row_a0 * EMB, wT + (size_t)row_b0 * EMB, acc);

  const int tid = threadIdx.x;
  const int w = tid >> 6, lane = tid & 63;
  const int lhi = lane >> 4, llo = lane & 15;
  const int wr = w >> 2, wc = w & 3;

  const int f0 = row_b0 + wc * 64;      // wave col base, 64-aligned
  const int part = f0 >> 10;            // 0=Q 1=K 2=V
  const int hh = (f0 & 1023) >> 6;      // head
  const int m_base = row_a0 + wr * 128;

  float bvals[4];
#pragma unroll
  for (int j = 0; j < 4; ++j) bvals[j] = bias[f0 + j * 16 + llo];

  if (part == 2) {
#pragma unroll
    for (int mi = 0; mi < 8; ++mi) {
      int m0 = m_base + mi * 16 + lhi * 4;
      int bb = m0 >> 11, pos0 = m0 & 2047;
#pragma unroll
      for (int j = 0; j < 4; ++j) {
        int dd = j * 16 + llo;
        bf16x4 pk;
#pragma unroll
        for (int r = 0; r < 4; ++r) pk[r] = (bf16)(acc[mi][j][r] + bvals[j]);
        *(bf16x4*)(vo + ((size_t)(bb * NH + hh) * HD + dd) * SEQ + pos0) = pk;
      }
    }
  } else {
    bf16* dst = (part == 0) ? qo : ko;
    const float qs = (part == 0) ? 0.125f : 1.0f;  // fold 1/sqrt(64) into Q (exact pow2)
#pragma unroll
    for (int mi = 0; mi < 8; ++mi) {
#pragma unroll
      for (int r = 0; r < 4; ++r) {
        int m = m_base + mi * 16 + lhi * 4 + r;
        int bb = m >> 11, pos = m & 2047;
        size_t base = ((size_t)(bb * NH + hh) * SEQ + pos) * HD;
#pragma unroll
        for (int j = 0; j < 2; ++j) {
          int d1 = j * 16 + llo;
          float x1 = acc[mi][j][r] + bvals[j];
          float x2 = acc[mi][j + 2][r] + bvals[j + 2];
          float cth = cosT[pos * 32 + d1];
          float sth = sinT[pos * 32 + d1];
          dst[base + d1] = (bf16)((x1 * cth - x2 * sth) * qs);
          dst[base + d1 + 32] = (bf16)((x2 * cth + x1 * sth) * qs);
        }
      }
    }
  }
}

// ---------------------------------------------------------------------------
// Output projection on the same 8-phase core.
// ---------------------------------------------------------------------------
__global__ __launch_bounds__(512, 2) void outproj8_kernel(
    const bf16* __restrict__ a_in, const bf16* __restrict__ wT,
    const float* __restrict__ bo, float* __restrict__ out) {
  extern __shared__ __align__(16) bf16 ldsb[];
  const int orig = blockIdx.x;
  const int wg = (orig & 7) * 16 + (orig >> 3);   // 128 % 8 == 0
  const int bx = wg % 4, by = wg / 4;
  const int row_a0 = by * 256, row_b0 = bx * 256;

  f32x4 acc[8][4];
  gemm256_core(ldsb, a_in + (size_t)row_a0 * EMB, wT + (size_t)row_b0 * EMB, acc);

  const int tid = threadIdx.x;
  const int w = tid >> 6, lane = tid & 63;
  const int lhi = lane >> 4, llo = lane & 15;
  const int wr = w >> 2, wc = w & 3;

  const int col0 = row_b0 + wc * 64;
  const int m_base = row_a0 + wr * 128;
  float bvals[4];
#pragma unroll
  for (int j = 0; j < 4; ++j) bvals[j] = bo[col0 + j * 16 + llo];
#pragma unroll
  for (int mi = 0; mi < 8; ++mi) {
#pragma unroll
    for (int r = 0; r < 4; ++r) {
      int m = m_base + mi * 16 + lhi * 4 + r;
#pragma unroll
      for (int j = 0; j < 4; ++j)
        out[(size_t)m * EMB + col0 + j * 16 + llo] = acc[mi][j][r] + bvals[j];
    }
  }
}

// ---------------------------------------------------------------------------
// Flash attention v5 (known-good, round-2 verified): 8 waves x 32 q-rows,
// 32x32x16 MFMA, swapped QK^T, in-register softmax, T12 P redistribution.
// ---------------------------------------------------------------------------
__global__ __launch_bounds__(512, 2) void attn32_kernel(const bf16* __restrict__ q,
                                                        const bf16* __restrict__ k,
                                                        const bf16* __restrict__ vT,
                                                        bf16* __restrict__ o) {
  __shared__ __align__(16) bf16 smem[16384];  // K dbuf 2x4096, V dbuf 2x4096 elems

  const int tid = threadIdx.x, w = tid >> 6, lane = tid & 63;
  const int l31 = lane & 31, hi = lane >> 5;
  const int bidx = blockIdx.x;
  const int vblk = (bidx & 7) * 64 + (bidx >> 3);  // XCD-contiguous remap (512 blocks)
  const int qt = vblk & 7, bh = vblk >> 3;         // 8 q-tiles of 256, bh in [0,64)
  const bf16* qbase = q + (size_t)bh * SEQ * HD + qt * 256 * HD;
  const bf16* kbase = k + (size_t)bh * SEQ * HD;
  const bf16* vbase = vT + (size_t)bh * HD * SEQ;

  const int rowc = lane >> 3;                     // row within 8-row chunk
  const int sw8 = (lane & 7) ^ rowc;              // staging XOR swizzle (16B granules)

  // Q -> registers: B-frag qf[c] = Q[q=l31][c*16 + hi*8 + j], rows w*32+l31
  bf16x8 qf[4];
  {
    const bf16* qrow = qbase + (size_t)(w * 32 + l31) * HD;
#pragma unroll
    for (int c = 0; c < 4; ++c) qf[c] = *(const bf16x8*)(qrow + c * 16 + hi * 8);
  }

  // stage tile 0: waves 0-3 K (64tok x 64d), waves 4-7 V^T (64d x 64tok)
  if (w < 4) {
#pragma unroll
    for (int c = 0; c < 2; ++c) {
      int ch = w * 2 + c, row = ch * 8 + rowc;
      gload_lds16(kbase + (size_t)row * HD + sw8 * 8, &smem[ch * 512]);
    }
  } else {
#pragma unroll
    for (int c = 0; c < 2; ++c) {
      int ch = (w - 4) * 2 + c, row = ch * 8 + rowc;
      gload_lds16(vbase + (size_t)row * SEQ + sw8 * 8, &smem[8192 + ch * 512]);
    }
  }
  __syncthreads();

  float rsum = 0.f;
  f32x16 oacc[2];
#pragma unroll
  for (int r = 0; r < 16; ++r) { oacc[0][r] = 0.f; oacc[1][r] = 0.f; }

  const int swz = (l31 & 7);  // row&7 for frag reads (rows = tile_base + l31)

  for (int kb = 0; kb < 32; ++kb) {
    bf16* Kc = smem + (kb & 1) * 4096;
    bf16* Vc = smem + 8192 + (kb & 1) * 4096;
    // prefetch next tile into alt buffers
    if (kb < 31) {
      int kpos = (kb + 1) * 64;
      if (w < 4) {
        bf16* Kn = smem + ((kb + 1) & 1) * 4096;
#pragma unroll
        for (int c = 0; c < 2; ++c) {
          int ch = w * 2 + c, row = ch * 8 + rowc;
          gload_lds16(kbase + (size_t)(kpos + row) * HD + sw8 * 8, &Kn[ch * 512]);
        }
      } else {
        bf16* Vn = smem + 8192 + ((kb + 1) & 1) * 4096;
#pragma unroll
        for (int c = 0; c < 2; ++c) {
          int ch = (w - 4) * 2 + c, row = ch * 8 + rowc;
          gload_lds16(vbase + (size_t)row * SEQ + kpos + sw8 * 8, &Vn[ch * 512]);
        }
      }
    }

    // ---- QK^T: S^T[tok][q], token tiles tt=0,1; k-chunks c of 16 dims
    f32x16 st0, st1;
#pragma unroll
    for (int r = 0; r < 16; ++r) { st0[r] = 0.f; st1[r] = 0.f; }
    __builtin_amdgcn_s_setprio(1);
#pragma unroll
    for (int c = 0; c < 4; ++c) {
      bf16x8 kf0 = *(const bf16x8*)&Kc[l31 * 64 + (((c * 2 + hi) ^ swz) * 8)];
      bf16x8 kf1 = *(const bf16x8*)&Kc[(32 + l31) * 64 + (((c * 2 + hi) ^ swz) * 8)];
      st0 = MFMA32(kf0, qf[c], st0);
      st1 = MFMA32(kf1, qf[c], st1);
    }
    __builtin_amdgcn_s_setprio(0);

    // ---- softmax: p = exp(s) in place (Q prescaled 1/8); tree-sum rsum
#pragma unroll
    for (int r = 0; r < 16; ++r) {
      st0[r] = __expf(st0[r]);
      st1[r] = __expf(st1[r]);
    }
    {
      float a0 = 0.f, a1 = 0.f, a2 = 0.f, a3 = 0.f;
#pragma unroll
      for (int r = 0; r < 16; r += 4) {
        a0 += st0[r];     a1 += st0[r + 1];
        a2 += st0[r + 2]; a3 += st0[r + 3];
      }
#pragma unroll
      for (int r = 0; r < 16; r += 4) {
        a0 += st1[r];     a1 += st1[r + 1];
        a2 += st1[r + 2]; a3 += st1[r + 3];
      }
      rsum += (a0 + a1) + (a2 + a3);
    }

    // ---- P -> PV A-frags (T12): per (tt,c1): 4 cvt_pk + 2 permlane32_swap.
    bf16x8 pa[4];
#pragma unroll
    for (int tt = 0; tt < 2; ++tt) {
#pragma unroll
      for (int c1 = 0; c1 < 2; ++c1) {
        float s0 = tt ? st1[c1 * 8 + 0] : st0[c1 * 8 + 0];
        float s1 = tt ? st1[c1 * 8 + 1] : st0[c1 * 8 + 1];
        float s2 = tt ? st1[c1 * 8 + 2] : st0[c1 * 8 + 2];
        float s3 = tt ? st1[c1 * 8 + 3] : st0[c1 * 8 + 3];
        float s4 = tt ? st1[c1 * 8 + 4] : st0[c1 * 8 + 4];
        float s5 = tt ? st1[c1 * 8 + 5] : st0[c1 * 8 + 5];
        float s6 = tt ? st1[c1 * 8 + 6] : st0[c1 * 8 + 6];
        float s7 = tt ? st1[c1 * 8 + 7] : st0[c1 * 8 + 7];
        uint32_t a0, a1, b0, b1;
        asm("v_cvt_pk_bf16_f32 %0, %1, %2" : "=v"(a0) : "v"(s0), "v"(s1));
        asm("v_cvt_pk_bf16_f32 %0, %1, %2" : "=v"(a1) : "v"(s2), "v"(s3));
        asm("v_cvt_pk_bf16_f32 %0, %1, %2" : "=v"(b0) : "v"(s4), "v"(s5));
        asm("v_cvt_pk_bf16_f32 %0, %1, %2" : "=v"(b1) : "v"(s6), "v"(s7));
        asm("v_permlane32_swap_b32 %0, %1" : "+v"(a0), "+v"(b0));
        asm("v_permlane32_swap_b32 %0, %1" : "+v"(a1), "+v"(b1));
        u32x4 uv = {a0, a1, b0, b1};
        pa[tt * 2 + c1] = __builtin_bit_cast(bf16x8, uv);
      }
    }

    // ---- O += P V : A=pa[c] (tokens c*16..+15), B=V^T rows d=jt*32+l31
    __builtin_amdgcn_s_setprio(1);
#pragma unroll
    for (int c = 0; c < 4; ++c) {
      bf16x8 v0 = *(const bf16x8*)&Vc[l31 * 64 + (((c * 2 + hi) ^ swz) * 8)];
      bf16x8 v1 = *(const bf16x8*)&Vc[(32 + l31) * 64 + (((c * 2 + hi) ^ swz) * 8)];
      oacc[0] = MFMA32(pa[c], v0, oacc[0]);
      oacc[1] = MFMA32(pa[c], v1, oacc[1]);
    }
    __builtin_amdgcn_s_setprio(0);

    __syncthreads();  // prefetch landed + guards buffer reuse
  }

  // epilogue: rsum(q=l31) split across lane halves -> combine; redistribute
  // to C-layout row owners via shfl; normalize and write.
  rsum += __shfl_xor(rsum, 32);
  const int bb = bh >> 4, hh = bh & 15;
#pragma unroll
  for (int r = 0; r < 16; ++r) {
    int qrow = (r & 3) + 8 * (r >> 2) + 4 * hi;
    float inv = 1.0f / __shfl(rsum, qrow);
    int pos = qt * 256 + w * 32 + qrow;
    size_t base = ((size_t)bb * SEQ + pos) * EMB + hh * HD;
    o[base + l31] = (bf16)(oacc[0][r] * inv);
    o[base + 32 + l31] = (bf16)(oacc[1][r] * inv);
  }
}

// ---------------------------------------------------------------------------
// Workspace layout (<= 64 MiB used):
//   [0, 16M)   qw [b,h,s,d] bf16   (later woT @0..2M after attn)
//   [16M,32M)  kw;  [32M,48M) vw [b,h,d,s]
//   [48M,64M)  phase1-2: wqkvT (6M) + cosT/sinT; phase3-4: ow bf16 (16M)
// d_out (33.5 MB f32) doubles as xb scratch (16.8 MB bf16) in phases 1-2.
// ---------------------------------------------------------------------------
extern "C" void kernel_launch(void* const* d_in, const int* in_sizes, int n_in,
                              void* d_out, int out_size, void* d_ws, size_t ws_size,
                              hipStream_t stream) {
  const float* x_raw = (const float*)d_in[0];
  const float* wqkv_raw = (const float*)d_in[1];
  const float* bqkv = (const float*)d_in[2];
  const float* wo_raw = (const float*)d_in[3];
  const float* bo = (const float*)d_in[4];
  float* out = (float*)d_out;

  char* ws = (char*)d_ws;
  bf16* qw = (bf16*)(ws);                       // 16 MiB
  bf16* kw = (bf16*)(ws + 16777216);            // 16 MiB
  bf16* vw = (bf16*)(ws + 33554432);            // 16 MiB
  bf16* wqkvT = (bf16*)(ws + 50331648);         // 6 MiB (phase 1-2)
  float* cosT = (float*)(ws + 56623104);        // 256 KiB (phase 1-2)
  float* sinT = (float*)(ws + 56885248);        // 256 KiB (phase 1-2)
  bf16* ow = (bf16*)(ws + 50331648);            // 16 MiB (phase 3-4, overlays above)
  bf16* woT = (bf16*)(ws);                      // 2 MiB (phase 3.5-4, overlays qw)
  bf16* xb = (bf16*)d_out;                      // 16.8 MiB scratch in d_out (phase 1-2)

  static bool attr_set = false;
  if (!attr_set) {
    (void)hipFuncSetAttribute((const void*)qkv8_kernel,
                              hipFuncAttributeMaxDynamicSharedMemorySize, 163840);
    (void)hipFuncSetAttribute((const void*)outproj8_kernel,
                              hipFuncAttributeMaxDynamicSharedMemorySize, 163840);
    attr_set = true;
  }

  prep_kernel<<<11520, 256, 0, stream>>>(x_raw, xb, wqkv_raw, wqkvT, cosT, sinT);

  qkv8_kernel<<<dim3((BATCH * SEQ / 256) * (F3 / 256)), 512, 163840, stream>>>(
      xb, wqkvT, bqkv, qw, kw, vw, cosT, sinT);
  attn32_kernel<<<dim3(BATCH * NH * (SEQ / 256)), 512, 0, stream>>>(qw, kw, vw, ow);

  transpose_f32_bf16<<<dim3(EMB / 32, EMB / 32), 256, 0, stream>>>(wo_raw, woT, EMB, EMB);
  outproj8_kernel<<<dim3((BATCH * SEQ / 256) * (EMB / 256)), 512, 163840, stream>>>(
      ow, woT, bo, out);
}

// Round 5
// 274.957 us; speedup vs baseline: 1.0571x; 1.0446x over previous
//
#include <hip/hip_runtime.h>
#include <stdint.h>
#include <stddef.h>

typedef __bf16 bf16;
typedef __attribute__((ext_vector_type(8))) __bf16 bf16x8;
typedef __attribute__((ext_vector_type(4))) __bf16 bf16x4;
typedef __attribute__((ext_vector_type(4))) float f32x4;
typedef __attribute__((ext_vector_type(16))) float f32x16;
typedef __attribute__((ext_vector_type(4))) float float4v;
typedef __attribute__((ext_vector_type(4))) uint32_t u32x4;

#define BATCH 4
#define SEQ   2048
#define EMB   1024
#define NH    16
#define HD    64
#define F3    3072   // 3*EMB

#define MFMA16(a, b, c) __builtin_amdgcn_mfma_f32_16x16x32_bf16((a), (b), (c), 0, 0, 0)
#define MFMA32(a, b, c) __builtin_amdgcn_mfma_f32_32x32x16_bf16((a), (b), (c), 0, 0, 0)

// async global->LDS, 16B per lane. lds ptr must be wave-uniform; lane i lands at l + i*16B.
__device__ __forceinline__ void gload_lds16(const bf16* g, bf16* l) {
  __builtin_amdgcn_global_load_lds(
      (const __attribute__((address_space(1))) uint32_t*)g,
      (__attribute__((address_space(3))) uint32_t*)l, 16, 0, 0);
}

// ---------------------------------------------------------------------------
// 32x32 tile transpose+convert helper (shared by prep_kernel and the wo pass).
// ---------------------------------------------------------------------------
__device__ __forceinline__ void transpose_tile32(const float* __restrict__ in,
                                                 bf16* __restrict__ out,
                                                 int R, int C, int bx, int by) {
  __shared__ bf16 tile[32][33];
  const int tx = threadIdx.x & 31;
  const int ty = threadIdx.x >> 5;  // 0..7
  const int c0 = bx * 32, r0 = by * 32;
#pragma unroll
  for (int kk = 0; kk < 4; ++kk) {
    int r = ty + kk * 8;
    tile[r][tx] = (bf16)in[(size_t)(r0 + r) * C + c0 + tx];
  }
  __syncthreads();
#pragma unroll
  for (int kk = 0; kk < 4; ++kk) {
    int r = ty + kk * 8;
    out[(size_t)(c0 + r) * R + r0 + tx] = tile[tx][r];
  }
}

// ---------------------------------------------------------------------------
// Fused prep: region-dispatched by blockIdx.
//   [0, 8192)        : convert x f32 -> bf16 (2M float4 groups, exact fit)
//   [8192, 11264)    : transpose wqkv [1024][3072] f32 -> wqkvT [3072][1024] bf16
//   [11264, 11520)   : RoPE cos/sin table (2048 pos x 32 d1, f32)
// ---------------------------------------------------------------------------
__global__ __launch_bounds__(256) void prep_kernel(const float* __restrict__ x_raw,
                                                   bf16* __restrict__ xb,
                                                   const float* __restrict__ wqkv_raw,
                                                   bf16* __restrict__ wqkvT,
                                                   float* __restrict__ cosT,
                                                   float* __restrict__ sinT) {
  const int blk = blockIdx.x;
  if (blk < 8192) {
    int i = blk * 256 + threadIdx.x;   // 8192*256 == BATCH*SEQ*EMB/4 exactly
    float4v v = ((const float4v*)x_raw)[i];
    bf16x4 o;
#pragma unroll
    for (int k = 0; k < 4; ++k) o[k] = (bf16)v[k];
    ((bf16x4*)xb)[i] = o;
  } else if (blk < 11264) {
    int idx = blk - 8192;              // 3072 tiles: 96 col-tiles x 32 row-tiles
    transpose_tile32(wqkv_raw, wqkvT, EMB, F3, idx % 96, idx / 96);
  } else {
    int idx = (blk - 11264) * 256 + threadIdx.x;   // 65536
    int pos = idx >> 5, d1 = idx & 31;
    float inv = powf(10000.0f, -(float)(2 * d1) / 64.0f);
    float th = (float)pos * inv;
    cosT[idx] = cosf(th);
    sinT[idx] = sinf(th);
  }
}

// ---------------------------------------------------------------------------
// Standalone transpose (wo only; must run after attn frees the woT region).
// ---------------------------------------------------------------------------
__global__ __launch_bounds__(256) void transpose_f32_bf16(const float* __restrict__ in,
                                                          bf16* __restrict__ out,
                                                          int R, int C) {
  transpose_tile32(in, out, R, C, blockIdx.x, blockIdx.y);
}

// ---------------------------------------------------------------------------
// 128x256 / BK=64 2-phase MFMA GEMM core, same verified schedule elements as
// the 256^2 core (STAGE macro, XOR swizzle, ka offsets, barrier/lgkm/setprio
// phase pattern, counted vmcnt) with a clean triple-buffered 9-slot ring:
//   slot = 16 KB = 128 rows x 64 k bf16. A tile = 1 slot, B tile = 2 slots.
//   tile t reads slots 3(t%3)..+2; during tile t we stage tile t+2 into the
//   slots of t-1 (whose reads completed at the end-of-(t-1) barrier).
//   vmcnt(6) at end of tile allows only t+2's 6 loads in flight => t+1 landed.
// 8 waves = 2M x 4N, per-wave C = 64x64 -> acc[4][4]. LDS 144 KB, 1 blk/CU.
// ---------------------------------------------------------------------------
__device__ __forceinline__ void gemm128_core(bf16* lds,
                                             const bf16* __restrict__ Abase,
                                             const bf16* __restrict__ Bbase,
                                             f32x4 (&acc)[4][4]) {
  const int tid = threadIdx.x;
  const int w = tid >> 6, lane = tid & 63;
  const int lhi = lane >> 4, llo = lane & 15, l7 = llo & 15 & 7;
  const int wr = w >> 2, wc = w & 3;          // 2M x 4N wave grid
  const int srow = lane >> 3;                 // staging row within 8-row chunk
  const int sk16 = (lane & 7) ^ srow;         // pre-swizzled global 16B granule
  const size_t g_lane = (size_t)(w * 16 + srow) * EMB + sk16 * 8;
  bf16* ldsw = lds + w * 1024;                // wave chunk base within a slot

  const int ka0 = (lhi * 8) ^ (l7 << 3);
  const int ka1 = (32 + lhi * 8) ^ (l7 << 3);
  const int arow = (wr * 64 + llo) * 64;            // A frag row base (elems)
  const int brow = ((wc & 1) * 64 + llo) * 64;      // B frag row base (elems)
  const int bsel = wc >> 1;                         // which B half-slot

#pragma unroll
  for (int i = 0; i < 4; ++i)
#pragma unroll
    for (int j = 0; j < 4; ++j) acc[i][j] = (f32x4){0.f, 0.f, 0.f, 0.f};

#define STAGE(baseptr, slot)                              \
  do {                                                    \
    const bf16* _b = (baseptr);                           \
    bf16* _l = ldsw + (slot) * 8192;                      \
    gload_lds16(_b + g_lane, _l);                         \
    gload_lds16(_b + g_lane + 8 * EMB, _l + 512);         \
  } while (0)

  // prologue: t0 -> slots 0,1,2 ; t1 -> slots 3,4,5
  STAGE(Abase, 0);
  STAGE(Bbase, 1);
  STAGE(Bbase + 128 * EMB, 2);
  STAGE(Abase + 64, 3);
  STAGE(Bbase + 64, 4);
  STAGE(Bbase + 128 * EMB + 64, 5);
  asm volatile("s_waitcnt vmcnt(6)" ::: "memory");  // t0's 6 loads landed
  __builtin_amdgcn_s_barrier();

  int s = 0;  // 3*(t%3)
#pragma unroll 1
  for (int t = 0; t < 16; ++t) {
    const bf16* ldsA = lds + s * 8192 + arow;
    const bf16* ldsB = lds + (s + 1 + bsel) * 8192 + brow;
    const int k2 = (t + 2) * 64;
    int st2 = s + 6;                 // 3*((t+2)%3) = slots of t-1
    if (st2 >= 9) st2 -= 9;
    bf16x8 a[4][2], b0[2][2], b1[2][2];

    // ---- phase 0: n-half0 -> acc[0..3][0..1]
#pragma unroll
    for (int i = 0; i < 4; ++i) {
      a[i][0] = *(const bf16x8*)(ldsA + i * 1024 + ka0);
      a[i][1] = *(const bf16x8*)(ldsA + i * 1024 + ka1);
    }
#pragma unroll
    for (int j = 0; j < 2; ++j) {
      b0[j][0] = *(const bf16x8*)(ldsB + j * 1024 + ka0);
      b0[j][1] = *(const bf16x8*)(ldsB + j * 1024 + ka1);
    }
    if (t < 14) {
      STAGE(Abase + k2, st2);
      STAGE(Bbase + k2, st2 + 1);
    }
    __builtin_amdgcn_s_barrier();
    asm volatile("s_waitcnt lgkmcnt(0)" ::: "memory");
    __builtin_amdgcn_sched_barrier(0);
    __builtin_amdgcn_s_setprio(1);
#pragma unroll
    for (int i = 0; i < 4; ++i)
#pragma unroll
      for (int j = 0; j < 2; ++j) {
        acc[i][j] = MFMA16(a[i][0], b0[j][0], acc[i][j]);
        acc[i][j] = MFMA16(a[i][1], b0[j][1], acc[i][j]);
      }
    __builtin_amdgcn_s_setprio(0);
    __builtin_amdgcn_s_barrier();

    // ---- phase 1: n-half1 -> acc[0..3][2..3]
#pragma unroll
    for (int j = 0; j < 2; ++j) {
      b1[j][0] = *(const bf16x8*)(ldsB + 2048 + j * 1024 + ka0);
      b1[j][1] = *(const bf16x8*)(ldsB + 2048 + j * 1024 + ka1);
    }
    if (t < 14) STAGE(Bbase + 128 * EMB + k2, st2 + 2);
    __builtin_amdgcn_s_barrier();
    asm volatile("s_waitcnt lgkmcnt(0)" ::: "memory");
    __builtin_amdgcn_sched_barrier(0);
    __builtin_amdgcn_s_setprio(1);
#pragma unroll
    for (int i = 0; i < 4; ++i)
#pragma unroll
      for (int j = 0; j < 2; ++j) {
        acc[i][2 + j] = MFMA16(a[i][0], b1[j][0], acc[i][2 + j]);
        acc[i][2 + j] = MFMA16(a[i][1], b1[j][1], acc[i][2 + j]);
      }
    __builtin_amdgcn_s_setprio(0);
    if (t < 14) {
      asm volatile("s_waitcnt vmcnt(6)" ::: "memory");
    } else if (t == 14) {
      asm volatile("s_waitcnt vmcnt(0)" ::: "memory");
    }
    if (t < 15) __builtin_amdgcn_s_barrier();

    s += 3;
    if (s >= 9) s -= 9;
  }
#undef STAGE
}

// ---------------------------------------------------------------------------
// QKV GEMM (128x256 core) + bias + RoPE + scatter epilogue.
// Grid 768 (64 Mtiles x 12 Ntiles) = exactly 3 rounds @ 1 blk/CU; 768%8==0.
// ---------------------------------------------------------------------------
__global__ __launch_bounds__(512, 2) void qkv128_kernel(
    const bf16* __restrict__ x, const bf16* __restrict__ wT,
    const float* __restrict__ bias, bf16* __restrict__ qo, bf16* __restrict__ ko,
    bf16* __restrict__ vo, const float* __restrict__ cosT,
    const float* __restrict__ sinT) {
  extern __shared__ __align__(16) bf16 ldsb[];
  const int orig = blockIdx.x;
  const int wg = (orig & 7) * 96 + (orig >> 3);   // 96 contiguous wgs per XCD
  const int bx = wg % 12, by = wg / 12;
  const int row_a0 = by * 128, row_b0 = bx * 256;

  f32x4 acc[4][4];
  gemm128_core(ldsb, x + (size_t)row_a0 * EMB, wT + (size_t)row_b0 * EMB, acc);

  const int tid = threadIdx.x;
  const int w = tid >> 6, lane = tid & 63;
  const int lhi = lane >> 4, llo = lane & 15;
  const int wr = w >> 2, wc = w & 3;

  const int f0 = row_b0 + wc * 64;      // wave col base, 64-aligned
  const int part = f0 >> 10;            // 0=Q 1=K 2=V
  const int hh = (f0 & 1023) >> 6;      // head
  const int m_base = row_a0 + wr * 64;

  float bvals[4];
#pragma unroll
  for (int j = 0; j < 4; ++j) bvals[j] = bias[f0 + j * 16 + llo];

  if (part == 2) {
#pragma unroll
    for (int mi = 0; mi < 4; ++mi) {
      int m0 = m_base + mi * 16 + lhi * 4;
      int bb = m0 >> 11, pos0 = m0 & 2047;
#pragma unroll
      for (int j = 0; j < 4; ++j) {
        int dd = j * 16 + llo;
        bf16x4 pk;
#pragma unroll
        for (int r = 0; r < 4; ++r) pk[r] = (bf16)(acc[mi][j][r] + bvals[j]);
        *(bf16x4*)(vo + ((size_t)(bb * NH + hh) * HD + dd) * SEQ + pos0) = pk;
      }
    }
  } else {
    bf16* dst = (part == 0) ? qo : ko;
    const float qs = (part == 0) ? 0.125f : 1.0f;  // fold 1/sqrt(64) into Q (exact pow2)
#pragma unroll
    for (int mi = 0; mi < 4; ++mi) {
#pragma unroll
      for (int r = 0; r < 4; ++r) {
        int m = m_base + mi * 16 + lhi * 4 + r;
        int bb = m >> 11, pos = m & 2047;
        size_t base = ((size_t)(bb * NH + hh) * SEQ + pos) * HD;
#pragma unroll
        for (int j = 0; j < 2; ++j) {
          int d1 = j * 16 + llo;
          float x1 = acc[mi][j][r] + bvals[j];
          float x2 = acc[mi][j + 2][r] + bvals[j + 2];
          float cth = cosT[pos * 32 + d1];
          float sth = sinT[pos * 32 + d1];
          dst[base + d1] = (bf16)((x1 * cth - x2 * sth) * qs);
          dst[base + d1 + 32] = (bf16)((x2 * cth + x1 * sth) * qs);
        }
      }
    }
  }
}

// ---------------------------------------------------------------------------
// Output projection on the 128x256 core. Grid 256 (64 x 4) = full GPU.
// ---------------------------------------------------------------------------
__global__ __launch_bounds__(512, 2) void outproj128_kernel(
    const bf16* __restrict__ a_in, const bf16* __restrict__ wT,
    const float* __restrict__ bo, float* __restrict__ out) {
  extern __shared__ __align__(16) bf16 ldsb[];
  const int orig = blockIdx.x;
  const int wg = (orig & 7) * 32 + (orig >> 3);   // 256 % 8 == 0
  const int bx = wg % 4, by = wg / 4;
  const int row_a0 = by * 128, row_b0 = bx * 256;

  f32x4 acc[4][4];
  gemm128_core(ldsb, a_in + (size_t)row_a0 * EMB, wT + (size_t)row_b0 * EMB, acc);

  const int tid = threadIdx.x;
  const int w = tid >> 6, lane = tid & 63;
  const int lhi = lane >> 4, llo = lane & 15;
  const int wr = w >> 2, wc = w & 3;

  const int col0 = row_b0 + wc * 64;
  const int m_base = row_a0 + wr * 64;
  float bvals[4];
#pragma unroll
  for (int j = 0; j < 4; ++j) bvals[j] = bo[col0 + j * 16 + llo];
#pragma unroll
  for (int mi = 0; mi < 4; ++mi) {
#pragma unroll
    for (int r = 0; r < 4; ++r) {
      int m = m_base + mi * 16 + lhi * 4 + r;
#pragma unroll
      for (int j = 0; j < 4; ++j)
        out[(size_t)m * EMB + col0 + j * 16 + llo] = acc[mi][j][r] + bvals[j];
    }
  }
}

// ---------------------------------------------------------------------------
// Flash attention v5 (known-good, round-2 verified): 8 waves x 32 q-rows,
// 32x32x16 MFMA, swapped QK^T, in-register softmax, T12 P redistribution.
// ---------------------------------------------------------------------------
__global__ __launch_bounds__(512, 2) void attn32_kernel(const bf16* __restrict__ q,
                                                        const bf16* __restrict__ k,
                                                        const bf16* __restrict__ vT,
                                                        bf16* __restrict__ o) {
  __shared__ __align__(16) bf16 smem[16384];  // K dbuf 2x4096, V dbuf 2x4096 elems

  const int tid = threadIdx.x, w = tid >> 6, lane = tid & 63;
  const int l31 = lane & 31, hi = lane >> 5;
  const int bidx = blockIdx.x;
  const int vblk = (bidx & 7) * 64 + (bidx >> 3);  // XCD-contiguous remap (512 blocks)
  const int qt = vblk & 7, bh = vblk >> 3;         // 8 q-tiles of 256, bh in [0,64)
  const bf16* qbase = q + (size_t)bh * SEQ * HD + qt * 256 * HD;
  const bf16* kbase = k + (size_t)bh * SEQ * HD;
  const bf16* vbase = vT + (size_t)bh * HD * SEQ;

  const int rowc = lane >> 3;                     // row within 8-row chunk
  const int sw8 = (lane & 7) ^ rowc;              // staging XOR swizzle (16B granules)

  // Q -> registers: B-frag qf[c] = Q[q=l31][c*16 + hi*8 + j], rows w*32+l31
  bf16x8 qf[4];
  {
    const bf16* qrow = qbase + (size_t)(w * 32 + l31) * HD;
#pragma unroll
    for (int c = 0; c < 4; ++c) qf[c] = *(const bf16x8*)(qrow + c * 16 + hi * 8);
  }

  // stage tile 0: waves 0-3 K (64tok x 64d), waves 4-7 V^T (64d x 64tok)
  if (w < 4) {
#pragma unroll
    for (int c = 0; c < 2; ++c) {
      int ch = w * 2 + c, row = ch * 8 + rowc;
      gload_lds16(kbase + (size_t)row * HD + sw8 * 8, &smem[ch * 512]);
    }
  } else {
#pragma unroll
    for (int c = 0; c < 2; ++c) {
      int ch = (w - 4) * 2 + c, row = ch * 8 + rowc;
      gload_lds16(vbase + (size_t)row * SEQ + sw8 * 8, &smem[8192 + ch * 512]);
    }
  }
  __syncthreads();

  float rsum = 0.f;
  f32x16 oacc[2];
#pragma unroll
  for (int r = 0; r < 16; ++r) { oacc[0][r] = 0.f; oacc[1][r] = 0.f; }

  const int swz = (l31 & 7);  // row&7 for frag reads (rows = tile_base + l31)

  for (int kb = 0; kb < 32; ++kb) {
    bf16* Kc = smem + (kb & 1) * 4096;
    bf16* Vc = smem + 8192 + (kb & 1) * 4096;
    // prefetch next tile into alt buffers
    if (kb < 31) {
      int kpos = (kb + 1) * 64;
      if (w < 4) {
        bf16* Kn = smem + ((kb + 1) & 1) * 4096;
#pragma unroll
        for (int c = 0; c < 2; ++c) {
          int ch = w * 2 + c, row = ch * 8 + rowc;
          gload_lds16(kbase + (size_t)(kpos + row) * HD + sw8 * 8, &Kn[ch * 512]);
        }
      } else {
        bf16* Vn = smem + 8192 + ((kb + 1) & 1) * 4096;
#pragma unroll
        for (int c = 0; c < 2; ++c) {
          int ch = (w - 4) * 2 + c, row = ch * 8 + rowc;
          gload_lds16(vbase + (size_t)row * SEQ + kpos + sw8 * 8, &Vn[ch * 512]);
        }
      }
    }

    // ---- QK^T: S^T[tok][q], token tiles tt=0,1; k-chunks c of 16 dims
    f32x16 st0, st1;
#pragma unroll
    for (int r = 0; r < 16; ++r) { st0[r] = 0.f; st1[r] = 0.f; }
    __builtin_amdgcn_s_setprio(1);
#pragma unroll
    for (int c = 0; c < 4; ++c) {
      bf16x8 kf0 = *(const bf16x8*)&Kc[l31 * 64 + (((c * 2 + hi) ^ swz) * 8)];
      bf16x8 kf1 = *(const bf16x8*)&Kc[(32 + l31) * 64 + (((c * 2 + hi) ^ swz) * 8)];
      st0 = MFMA32(kf0, qf[c], st0);
      st1 = MFMA32(kf1, qf[c], st1);
    }
    __builtin_amdgcn_s_setprio(0);

    // ---- softmax: p = exp(s) in place (Q prescaled 1/8); tree-sum rsum
#pragma unroll
    for (int r = 0; r < 16; ++r) {
      st0[r] = __expf(st0[r]);
      st1[r] = __expf(st1[r]);
    }
    {
      float a0 = 0.f, a1 = 0.f, a2 = 0.f, a3 = 0.f;
#pragma unroll
      for (int r = 0; r < 16; r += 4) {
        a0 += st0[r];     a1 += st0[r + 1];
        a2 += st0[r + 2]; a3 += st0[r + 3];
      }
#pragma unroll
      for (int r = 0; r < 16; r += 4) {
        a0 += st1[r];     a1 += st1[r + 1];
        a2 += st1[r + 2]; a3 += st1[r + 3];
      }
      rsum += (a0 + a1) + (a2 + a3);
    }

    // ---- P -> PV A-frags (T12): per (tt,c1): 4 cvt_pk + 2 permlane32_swap.
    bf16x8 pa[4];
#pragma unroll
    for (int tt = 0; tt < 2; ++tt) {
#pragma unroll
      for (int c1 = 0; c1 < 2; ++c1) {
        float s0 = tt ? st1[c1 * 8 + 0] : st0[c1 * 8 + 0];
        float s1 = tt ? st1[c1 * 8 + 1] : st0[c1 * 8 + 1];
        float s2 = tt ? st1[c1 * 8 + 2] : st0[c1 * 8 + 2];
        float s3 = tt ? st1[c1 * 8 + 3] : st0[c1 * 8 + 3];
        float s4 = tt ? st1[c1 * 8 + 4] : st0[c1 * 8 + 4];
        float s5 = tt ? st1[c1 * 8 + 5] : st0[c1 * 8 + 5];
        float s6 = tt ? st1[c1 * 8 + 6] : st0[c1 * 8 + 6];
        float s7 = tt ? st1[c1 * 8 + 7] : st0[c1 * 8 + 7];
        uint32_t a0, a1, b0, b1;
        asm("v_cvt_pk_bf16_f32 %0, %1, %2" : "=v"(a0) : "v"(s0), "v"(s1));
        asm("v_cvt_pk_bf16_f32 %0, %1, %2" : "=v"(a1) : "v"(s2), "v"(s3));
        asm("v_cvt_pk_bf16_f32 %0, %1, %2" : "=v"(b0) : "v"(s4), "v"(s5));
        asm("v_cvt_pk_bf16_f32 %0, %1, %2" : "=v"(b1) : "v"(s6), "v"(s7));
        asm("v_permlane32_swap_b32 %0, %1" : "+v"(a0), "+v"(b0));
        asm("v_permlane32_swap_b32 %0, %1" : "+v"(a1), "+v"(b1));
        u32x4 uv = {a0, a1, b0, b1};
        pa[tt * 2 + c1] = __builtin_bit_cast(bf16x8, uv);
      }
    }

    // ---- O += P V : A=pa[c] (tokens c*16..+15), B=V^T rows d=jt*32+l31
    __builtin_amdgcn_s_setprio(1);
#pragma unroll
    for (int c = 0; c < 4; ++c) {
      bf16x8 v0 = *(const bf16x8*)&Vc[l31 * 64 + (((c * 2 + hi) ^ swz) * 8)];
      bf16x8 v1 = *(const bf16x8*)&Vc[(32 + l31) * 64 + (((c * 2 + hi) ^ swz) * 8)];
      oacc[0] = MFMA32(pa[c], v0, oacc[0]);
      oacc[1] = MFMA32(pa[c], v1, oacc[1]);
    }
    __builtin_amdgcn_s_setprio(0);

    __syncthreads();  // prefetch landed + guards buffer reuse
  }

  // epilogue: rsum(q=l31) split across lane halves -> combine; redistribute
  // to C-layout row owners via shfl; normalize and write.
  rsum += __shfl_xor(rsum, 32);
  const int bb = bh >> 4, hh = bh & 15;
#pragma unroll
  for (int r = 0; r < 16; ++r) {
    int qrow = (r & 3) + 8 * (r >> 2) + 4 * hi;
    float inv = 1.0f / __shfl(rsum, qrow);
    int pos = qt * 256 + w * 32 + qrow;
    size_t base = ((size_t)bb * SEQ + pos) * EMB + hh * HD;
    o[base + l31] = (bf16)(oacc[0][r] * inv);
    o[base + 32 + l31] = (bf16)(oacc[1][r] * inv);
  }
}

// ---------------------------------------------------------------------------
// Workspace layout (<= 64 MiB used):
//   [0, 16M)   qw [b,h,s,d] bf16   (later woT @0..2M after attn)
//   [16M,32M)  kw;  [32M,48M) vw [b,h,d,s]
//   [48M,64M)  phase1-2: wqkvT (6M) + cosT/sinT; phase3-4: ow bf16 (16M)
// d_out (33.5 MB f32) doubles as xb scratch (16.8 MB bf16) in phases 1-2.
// ---------------------------------------------------------------------------
extern "C" void kernel_launch(void* const* d_in, const int* in_sizes, int n_in,
                              void* d_out, int out_size, void* d_ws, size_t ws_size,
                              hipStream_t stream) {
  const float* x_raw = (const float*)d_in[0];
  const float* wqkv_raw = (const float*)d_in[1];
  const float* bqkv = (const float*)d_in[2];
  const float* wo_raw = (const float*)d_in[3];
  const float* bo = (const float*)d_in[4];
  float* out = (float*)d_out;

  char* ws = (char*)d_ws;
  bf16* qw = (bf16*)(ws);                       // 16 MiB
  bf16* kw = (bf16*)(ws + 16777216);            // 16 MiB
  bf16* vw = (bf16*)(ws + 33554432);            // 16 MiB
  bf16* wqkvT = (bf16*)(ws + 50331648);         // 6 MiB (phase 1-2)
  float* cosT = (float*)(ws + 56623104);        // 256 KiB (phase 1-2)
  float* sinT = (float*)(ws + 56885248);        // 256 KiB (phase 1-2)
  bf16* ow = (bf16*)(ws + 50331648);            // 16 MiB (phase 3-4, overlays above)
  bf16* woT = (bf16*)(ws);                      // 2 MiB (phase 3.5-4, overlays qw)
  bf16* xb = (bf16*)d_out;                      // 16.8 MiB scratch in d_out (phase 1-2)

  static bool attr_set = false;
  if (!attr_set) {
    (void)hipFuncSetAttribute((const void*)qkv128_kernel,
                              hipFuncAttributeMaxDynamicSharedMemorySize, 163840);
    (void)hipFuncSetAttribute((const void*)outproj128_kernel,
                              hipFuncAttributeMaxDynamicSharedMemorySize, 163840);
    attr_set = true;
  }

  prep_kernel<<<11520, 256, 0, stream>>>(x_raw, xb, wqkv_raw, wqkvT, cosT, sinT);

  qkv128_kernel<<<dim3((BATCH * SEQ / 128) * (F3 / 256)), 512, 147456, stream>>>(
      xb, wqkvT, bqkv, qw, kw, vw, cosT, sinT);
  attn32_kernel<<<dim3(BATCH * NH * (SEQ / 256)), 512, 0, stream>>>(qw, kw, vw, ow);

  transpose_f32_bf16<<<dim3(EMB / 32, EMB / 32), 256, 0, stream>>>(wo_raw, woT, EMB, EMB);
  outproj128_kernel<<<dim3((BATCH * SEQ / 128) * (EMB / 256)), 512, 147456, stream>>>(
      ow, woT, bo, out);
}

// Round 6
// 264.523 us; speedup vs baseline: 1.0988x; 1.0394x over previous
//
#include <hip/hip_runtime.h>
#include <stdint.h>
#include <stddef.h>

typedef __bf16 bf16;
typedef __attribute__((ext_vector_type(8))) __bf16 bf16x8;
typedef __attribute__((ext_vector_type(4))) __bf16 bf16x4;
typedef __attribute__((ext_vector_type(4))) float f32x4;
typedef __attribute__((ext_vector_type(16))) float f32x16;
typedef __attribute__((ext_vector_type(4))) float float4v;
typedef __attribute__((ext_vector_type(4))) uint32_t u32x4;

#define BATCH 4
#define SEQ   2048
#define EMB   1024
#define NH    16
#define HD    64
#define F3    3072   // 3*EMB

#define MFMA16(a, b, c) __builtin_amdgcn_mfma_f32_16x16x32_bf16((a), (b), (c), 0, 0, 0)
#define MFMA32(a, b, c) __builtin_amdgcn_mfma_f32_32x32x16_bf16((a), (b), (c), 0, 0, 0)

// async global->LDS, 16B per lane. lds ptr must be wave-uniform; lane i lands at l + i*16B.
__device__ __forceinline__ void gload_lds16(const bf16* g, bf16* l) {
  __builtin_amdgcn_global_load_lds(
      (const __attribute__((address_space(1))) uint32_t*)g,
      (__attribute__((address_space(3))) uint32_t*)l, 16, 0, 0);
}

// ---------------------------------------------------------------------------
// 32x32 tile transpose+convert helper (shared by prep_kernel and the wo pass).
// ---------------------------------------------------------------------------
__device__ __forceinline__ void transpose_tile32(const float* __restrict__ in,
                                                 bf16* __restrict__ out,
                                                 int R, int C, int bx, int by) {
  __shared__ bf16 tile[32][33];
  const int tx = threadIdx.x & 31;
  const int ty = threadIdx.x >> 5;  // 0..7
  const int c0 = bx * 32, r0 = by * 32;
#pragma unroll
  for (int kk = 0; kk < 4; ++kk) {
    int r = ty + kk * 8;
    tile[r][tx] = (bf16)in[(size_t)(r0 + r) * C + c0 + tx];
  }
  __syncthreads();
#pragma unroll
  for (int kk = 0; kk < 4; ++kk) {
    int r = ty + kk * 8;
    out[(size_t)(c0 + r) * R + r0 + tx] = tile[tx][r];
  }
}

// ---------------------------------------------------------------------------
// Fused prep: region-dispatched by blockIdx.
//   [0, 8192)        : convert x f32 -> bf16 (2M float4 groups, exact fit)
//   [8192, 11264)    : transpose wqkv [1024][3072] f32 -> wqkvT [3072][1024] bf16
//   [11264, 11520)   : RoPE cos/sin table (2048 pos x 32 d1, f32)
// ---------------------------------------------------------------------------
__global__ __launch_bounds__(256) void prep_kernel(const float* __restrict__ x_raw,
                                                   bf16* __restrict__ xb,
                                                   const float* __restrict__ wqkv_raw,
                                                   bf16* __restrict__ wqkvT,
                                                   float* __restrict__ cosT,
                                                   float* __restrict__ sinT) {
  const int blk = blockIdx.x;
  if (blk < 8192) {
    int i = blk * 256 + threadIdx.x;   // 8192*256 == BATCH*SEQ*EMB/4 exactly
    float4v v = ((const float4v*)x_raw)[i];
    bf16x4 o;
#pragma unroll
    for (int k = 0; k < 4; ++k) o[k] = (bf16)v[k];
    ((bf16x4*)xb)[i] = o;
  } else if (blk < 11264) {
    int idx = blk - 8192;              // 3072 tiles: 96 col-tiles x 32 row-tiles
    transpose_tile32(wqkv_raw, wqkvT, EMB, F3, idx % 96, idx / 96);
  } else {
    int idx = (blk - 11264) * 256 + threadIdx.x;   // 65536
    int pos = idx >> 5, d1 = idx & 31;
    float inv = powf(10000.0f, -(float)(2 * d1) / 64.0f);
    float th = (float)pos * inv;
    cosT[idx] = cosf(th);
    sinT[idx] = sinf(th);
  }
}

// ---------------------------------------------------------------------------
// Standalone transpose (wo only; must run after attn frees the woT region).
// ---------------------------------------------------------------------------
__global__ __launch_bounds__(256) void transpose_f32_bf16(const float* __restrict__ in,
                                                          bf16* __restrict__ out,
                                                          int R, int C) {
  transpose_tile32(in, out, R, C, blockIdx.x, blockIdx.y);
}

// ---------------------------------------------------------------------------
// 128x256 / BK=64 2-phase MFMA GEMM core (unchanged, round-5 verified).
// ---------------------------------------------------------------------------
__device__ __forceinline__ void gemm128_core(bf16* lds,
                                             const bf16* __restrict__ Abase,
                                             const bf16* __restrict__ Bbase,
                                             f32x4 (&acc)[4][4]) {
  const int tid = threadIdx.x;
  const int w = tid >> 6, lane = tid & 63;
  const int lhi = lane >> 4, llo = lane & 15, l7 = llo & 15 & 7;
  const int wr = w >> 2, wc = w & 3;          // 2M x 4N wave grid
  const int srow = lane >> 3;                 // staging row within 8-row chunk
  const int sk16 = (lane & 7) ^ srow;         // pre-swizzled global 16B granule
  const size_t g_lane = (size_t)(w * 16 + srow) * EMB + sk16 * 8;
  bf16* ldsw = lds + w * 1024;                // wave chunk base within a slot

  const int ka0 = (lhi * 8) ^ (l7 << 3);
  const int ka1 = (32 + lhi * 8) ^ (l7 << 3);
  const int arow = (wr * 64 + llo) * 64;            // A frag row base (elems)
  const int brow = ((wc & 1) * 64 + llo) * 64;      // B frag row base (elems)
  const int bsel = wc >> 1;                         // which B half-slot

#pragma unroll
  for (int i = 0; i < 4; ++i)
#pragma unroll
    for (int j = 0; j < 4; ++j) acc[i][j] = (f32x4){0.f, 0.f, 0.f, 0.f};

#define STAGE(baseptr, slot)                              \
  do {                                                    \
    const bf16* _b = (baseptr);                           \
    bf16* _l = ldsw + (slot) * 8192;                      \
    gload_lds16(_b + g_lane, _l);                         \
    gload_lds16(_b + g_lane + 8 * EMB, _l + 512);         \
  } while (0)

  // prologue: t0 -> slots 0,1,2 ; t1 -> slots 3,4,5
  STAGE(Abase, 0);
  STAGE(Bbase, 1);
  STAGE(Bbase + 128 * EMB, 2);
  STAGE(Abase + 64, 3);
  STAGE(Bbase + 64, 4);
  STAGE(Bbase + 128 * EMB + 64, 5);
  asm volatile("s_waitcnt vmcnt(6)" ::: "memory");  // t0's 6 loads landed
  __builtin_amdgcn_s_barrier();

  int s = 0;  // 3*(t%3)
#pragma unroll 1
  for (int t = 0; t < 16; ++t) {
    const bf16* ldsA = lds + s * 8192 + arow;
    const bf16* ldsB = lds + (s + 1 + bsel) * 8192 + brow;
    const int k2 = (t + 2) * 64;
    int st2 = s + 6;                 // 3*((t+2)%3) = slots of t-1
    if (st2 >= 9) st2 -= 9;
    bf16x8 a[4][2], b0[2][2], b1[2][2];

    // ---- phase 0: n-half0 -> acc[0..3][0..1]
#pragma unroll
    for (int i = 0; i < 4; ++i) {
      a[i][0] = *(const bf16x8*)(ldsA + i * 1024 + ka0);
      a[i][1] = *(const bf16x8*)(ldsA + i * 1024 + ka1);
    }
#pragma unroll
    for (int j = 0; j < 2; ++j) {
      b0[j][0] = *(const bf16x8*)(ldsB + j * 1024 + ka0);
      b0[j][1] = *(const bf16x8*)(ldsB + j * 1024 + ka1);
    }
    if (t < 14) {
      STAGE(Abase + k2, st2);
      STAGE(Bbase + k2, st2 + 1);
    }
    __builtin_amdgcn_s_barrier();
    asm volatile("s_waitcnt lgkmcnt(0)" ::: "memory");
    __builtin_amdgcn_sched_barrier(0);
    __builtin_amdgcn_s_setprio(1);
#pragma unroll
    for (int i = 0; i < 4; ++i)
#pragma unroll
      for (int j = 0; j < 2; ++j) {
        acc[i][j] = MFMA16(a[i][0], b0[j][0], acc[i][j]);
        acc[i][j] = MFMA16(a[i][1], b0[j][1], acc[i][j]);
      }
    __builtin_amdgcn_s_setprio(0);
    __builtin_amdgcn_s_barrier();

    // ---- phase 1: n-half1 -> acc[0..3][2..3]
#pragma unroll
    for (int j = 0; j < 2; ++j) {
      b1[j][0] = *(const bf16x8*)(ldsB + 2048 + j * 1024 + ka0);
      b1[j][1] = *(const bf16x8*)(ldsB + 2048 + j * 1024 + ka1);
    }
    if (t < 14) STAGE(Bbase + 128 * EMB + k2, st2 + 2);
    __builtin_amdgcn_s_barrier();
    asm volatile("s_waitcnt lgkmcnt(0)" ::: "memory");
    __builtin_amdgcn_sched_barrier(0);
    __builtin_amdgcn_s_setprio(1);
#pragma unroll
    for (int i = 0; i < 4; ++i)
#pragma unroll
      for (int j = 0; j < 2; ++j) {
        acc[i][2 + j] = MFMA16(a[i][0], b1[j][0], acc[i][2 + j]);
        acc[i][2 + j] = MFMA16(a[i][1], b1[j][1], acc[i][2 + j]);
      }
    __builtin_amdgcn_s_setprio(0);
    if (t < 14) {
      asm volatile("s_waitcnt vmcnt(6)" ::: "memory");
    } else if (t == 14) {
      asm volatile("s_waitcnt vmcnt(0)" ::: "memory");
    }
    if (t < 15) __builtin_amdgcn_s_barrier();

    s += 3;
    if (s >= 9) s -= 9;
  }
#undef STAGE
}

// ---------------------------------------------------------------------------
// QKV GEMM (128x256 core) + bias + RoPE + scatter epilogue.
// Grid 768 (64 Mtiles x 12 Ntiles) = exactly 3 rounds @ 1 blk/CU; 768%8==0.
// ---------------------------------------------------------------------------
__global__ __launch_bounds__(512, 2) void qkv128_kernel(
    const bf16* __restrict__ x, const bf16* __restrict__ wT,
    const float* __restrict__ bias, bf16* __restrict__ qo, bf16* __restrict__ ko,
    bf16* __restrict__ vo, const float* __restrict__ cosT,
    const float* __restrict__ sinT) {
  extern __shared__ __align__(16) bf16 ldsb[];
  const int orig = blockIdx.x;
  const int wg = (orig & 7) * 96 + (orig >> 3);   // 96 contiguous wgs per XCD
  const int bx = wg % 12, by = wg / 12;
  const int row_a0 = by * 128, row_b0 = bx * 256;

  f32x4 acc[4][4];
  gemm128_core(ldsb, x + (size_t)row_a0 * EMB, wT + (size_t)row_b0 * EMB, acc);

  const int tid = threadIdx.x;
  const int w = tid >> 6, lane = tid & 63;
  const int lhi = lane >> 4, llo = lane & 15;
  const int wr = w >> 2, wc = w & 3;

  const int f0 = row_b0 + wc * 64;      // wave col base, 64-aligned
  const int part = f0 >> 10;            // 0=Q 1=K 2=V
  const int hh = (f0 & 1023) >> 6;      // head
  const int m_base = row_a0 + wr * 64;

  float bvals[4];
#pragma unroll
  for (int j = 0; j < 4; ++j) bvals[j] = bias[f0 + j * 16 + llo];

  if (part == 2) {
#pragma unroll
    for (int mi = 0; mi < 4; ++mi) {
      int m0 = m_base + mi * 16 + lhi * 4;
      int bb = m0 >> 11, pos0 = m0 & 2047;
#pragma unroll
      for (int j = 0; j < 4; ++j) {
        int dd = j * 16 + llo;
        bf16x4 pk;
#pragma unroll
        for (int r = 0; r < 4; ++r) pk[r] = (bf16)(acc[mi][j][r] + bvals[j]);
        *(bf16x4*)(vo + ((size_t)(bb * NH + hh) * HD + dd) * SEQ + pos0) = pk;
      }
    }
  } else {
    bf16* dst = (part == 0) ? qo : ko;
    const float qs = (part == 0) ? 0.125f : 1.0f;  // fold 1/sqrt(64) into Q (exact pow2)
#pragma unroll
    for (int mi = 0; mi < 4; ++mi) {
#pragma unroll
      for (int r = 0; r < 4; ++r) {
        int m = m_base + mi * 16 + lhi * 4 + r;
        int bb = m >> 11, pos = m & 2047;
        size_t base = ((size_t)(bb * NH + hh) * SEQ + pos) * HD;
#pragma unroll
        for (int j = 0; j < 2; ++j) {
          int d1 = j * 16 + llo;
          float x1 = acc[mi][j][r] + bvals[j];
          float x2 = acc[mi][j + 2][r] + bvals[j + 2];
          float cth = cosT[pos * 32 + d1];
          float sth = sinT[pos * 32 + d1];
          dst[base + d1] = (bf16)((x1 * cth - x2 * sth) * qs);
          dst[base + d1 + 32] = (bf16)((x2 * cth + x1 * sth) * qs);
        }
      }
    }
  }
}

// ---------------------------------------------------------------------------
// Output projection on the 128x256 core. Grid 256 (64 x 4) = full GPU.
// ---------------------------------------------------------------------------
__global__ __launch_bounds__(512, 2) void outproj128_kernel(
    const bf16* __restrict__ a_in, const bf16* __restrict__ wT,
    const float* __restrict__ bo, float* __restrict__ out) {
  extern __shared__ __align__(16) bf16 ldsb[];
  const int orig = blockIdx.x;
  const int wg = (orig & 7) * 32 + (orig >> 3);   // 256 % 8 == 0
  const int bx = wg % 4, by = wg / 4;
  const int row_a0 = by * 128, row_b0 = bx * 256;

  f32x4 acc[4][4];
  gemm128_core(ldsb, a_in + (size_t)row_a0 * EMB, wT + (size_t)row_b0 * EMB, acc);

  const int tid = threadIdx.x;
  const int w = tid >> 6, lane = tid & 63;
  const int lhi = lane >> 4, llo = lane & 15;
  const int wr = w >> 2, wc = w & 3;

  const int col0 = row_b0 + wc * 64;
  const int m_base = row_a0 + wr * 64;
  float bvals[4];
#pragma unroll
  for (int j = 0; j < 4; ++j) bvals[j] = bo[col0 + j * 16 + llo];
#pragma unroll
  for (int mi = 0; mi < 4; ++mi) {
#pragma unroll
    for (int r = 0; r < 4; ++r) {
      int m = m_base + mi * 16 + lhi * 4 + r;
#pragma unroll
      for (int j = 0; j < 4; ++j)
        out[(size_t)m * EMB + col0 + j * 16 + llo] = acc[mi][j][r] + bvals[j];
    }
  }
}

// ---------------------------------------------------------------------------
// Flash attention v6a: round-2-verified v5 + ONE change (R3 candidate (c),
// landed alone): row-sum via MFMA-ones into racc. D[q][n] = sum_k P[q][k]
// lands in the same C-layout as oacc (m74/m101 mapping), the MFMA K-reduction
// spans both lane halves, so the VALU sum tree AND all epilogue shuffles go
// away; denominator now uses the same bf16 P as the numerator.
// ---------------------------------------------------------------------------
__global__ __launch_bounds__(512, 2) void attn32_kernel(const bf16* __restrict__ q,
                                                        const bf16* __restrict__ k,
                                                        const bf16* __restrict__ vT,
                                                        bf16* __restrict__ o) {
  __shared__ __align__(16) bf16 smem[16384];  // K dbuf 2x4096, V dbuf 2x4096 elems

  const int tid = threadIdx.x, w = tid >> 6, lane = tid & 63;
  const int l31 = lane & 31, hi = lane >> 5;
  const int bidx = blockIdx.x;
  const int vblk = (bidx & 7) * 64 + (bidx >> 3);  // XCD-contiguous remap (512 blocks)
  const int qt = vblk & 7, bh = vblk >> 3;         // 8 q-tiles of 256, bh in [0,64)
  const bf16* qbase = q + (size_t)bh * SEQ * HD + qt * 256 * HD;
  const bf16* kbase = k + (size_t)bh * SEQ * HD;
  const bf16* vbase = vT + (size_t)bh * HD * SEQ;

  const int rowc = lane >> 3;                     // row within 8-row chunk
  const int sw8 = (lane & 7) ^ rowc;              // staging XOR swizzle (16B granules)

  // Q -> registers: B-frag qf[c] = Q[q=l31][c*16 + hi*8 + j], rows w*32+l31
  bf16x8 qf[4];
  {
    const bf16* qrow = qbase + (size_t)(w * 32 + l31) * HD;
#pragma unroll
    for (int c = 0; c < 4; ++c) qf[c] = *(const bf16x8*)(qrow + c * 16 + hi * 8);
  }

  // stage tile 0: waves 0-3 K (64tok x 64d), waves 4-7 V^T (64d x 64tok)
  if (w < 4) {
#pragma unroll
    for (int c = 0; c < 2; ++c) {
      int ch = w * 2 + c, row = ch * 8 + rowc;
      gload_lds16(kbase + (size_t)row * HD + sw8 * 8, &smem[ch * 512]);
    }
  } else {
#pragma unroll
    for (int c = 0; c < 2; ++c) {
      int ch = (w - 4) * 2 + c, row = ch * 8 + rowc;
      gload_lds16(vbase + (size_t)row * SEQ + sw8 * 8, &smem[8192 + ch * 512]);
    }
  }
  __syncthreads();

  f32x16 oacc[2], racc;
#pragma unroll
  for (int r = 0; r < 16; ++r) { oacc[0][r] = 0.f; oacc[1][r] = 0.f; racc[r] = 0.f; }

  // all-ones B-frag: B[k][n] = 1 -> D[q][n] = sum_k P[q][k] (any n)
  bf16x8 onesf;
#pragma unroll
  for (int j = 0; j < 8; ++j) onesf[j] = (bf16)1.0f;

  const int swz = (l31 & 7);  // row&7 for frag reads (rows = tile_base + l31)

  for (int kb = 0; kb < 32; ++kb) {
    bf16* Kc = smem + (kb & 1) * 4096;
    bf16* Vc = smem + 8192 + (kb & 1) * 4096;
    // prefetch next tile into alt buffers
    if (kb < 31) {
      int kpos = (kb + 1) * 64;
      if (w < 4) {
        bf16* Kn = smem + ((kb + 1) & 1) * 4096;
#pragma unroll
        for (int c = 0; c < 2; ++c) {
          int ch = w * 2 + c, row = ch * 8 + rowc;
          gload_lds16(kbase + (size_t)(kpos + row) * HD + sw8 * 8, &Kn[ch * 512]);
        }
      } else {
        bf16* Vn = smem + 8192 + ((kb + 1) & 1) * 4096;
#pragma unroll
        for (int c = 0; c < 2; ++c) {
          int ch = (w - 4) * 2 + c, row = ch * 8 + rowc;
          gload_lds16(vbase + (size_t)row * SEQ + kpos + sw8 * 8, &Vn[ch * 512]);
        }
      }
    }

    // ---- QK^T: S^T[tok][q], token tiles tt=0,1; k-chunks c of 16 dims
    f32x16 st0, st1;
#pragma unroll
    for (int r = 0; r < 16; ++r) { st0[r] = 0.f; st1[r] = 0.f; }
    __builtin_amdgcn_s_setprio(1);
#pragma unroll
    for (int c = 0; c < 4; ++c) {
      bf16x8 kf0 = *(const bf16x8*)&Kc[l31 * 64 + (((c * 2 + hi) ^ swz) * 8)];
      bf16x8 kf1 = *(const bf16x8*)&Kc[(32 + l31) * 64 + (((c * 2 + hi) ^ swz) * 8)];
      st0 = MFMA32(kf0, qf[c], st0);
      st1 = MFMA32(kf1, qf[c], st1);
    }
    __builtin_amdgcn_s_setprio(0);

    // ---- softmax: p = exp(s) in place (Q prescaled 1/8)
#pragma unroll
    for (int r = 0; r < 16; ++r) {
      st0[r] = __expf(st0[r]);
      st1[r] = __expf(st1[r]);
    }

    // ---- P -> PV A-frags (T12): per (tt,c1): 4 cvt_pk + 2 permlane32_swap.
    bf16x8 pa[4];
#pragma unroll
    for (int tt = 0; tt < 2; ++tt) {
#pragma unroll
      for (int c1 = 0; c1 < 2; ++c1) {
        float s0 = tt ? st1[c1 * 8 + 0] : st0[c1 * 8 + 0];
        float s1 = tt ? st1[c1 * 8 + 1] : st0[c1 * 8 + 1];
        float s2 = tt ? st1[c1 * 8 + 2] : st0[c1 * 8 + 2];
        float s3 = tt ? st1[c1 * 8 + 3] : st0[c1 * 8 + 3];
        float s4 = tt ? st1[c1 * 8 + 4] : st0[c1 * 8 + 4];
        float s5 = tt ? st1[c1 * 8 + 5] : st0[c1 * 8 + 5];
        float s6 = tt ? st1[c1 * 8 + 6] : st0[c1 * 8 + 6];
        float s7 = tt ? st1[c1 * 8 + 7] : st0[c1 * 8 + 7];
        uint32_t a0, a1, b0, b1;
        asm("v_cvt_pk_bf16_f32 %0, %1, %2" : "=v"(a0) : "v"(s0), "v"(s1));
        asm("v_cvt_pk_bf16_f32 %0, %1, %2" : "=v"(a1) : "v"(s2), "v"(s3));
        asm("v_cvt_pk_bf16_f32 %0, %1, %2" : "=v"(b0) : "v"(s4), "v"(s5));
        asm("v_cvt_pk_bf16_f32 %0, %1, %2" : "=v"(b1) : "v"(s6), "v"(s7));
        asm("v_permlane32_swap_b32 %0, %1" : "+v"(a0), "+v"(b0));
        asm("v_permlane32_swap_b32 %0, %1" : "+v"(a1), "+v"(b1));
        u32x4 uv = {a0, a1, b0, b1};
        pa[tt * 2 + c1] = __builtin_bit_cast(bf16x8, uv);
      }
    }

    // ---- O += P V ; racc += P * ones (row-sum on the MFMA pipe)
    __builtin_amdgcn_s_setprio(1);
#pragma unroll
    for (int c = 0; c < 4; ++c) {
      bf16x8 v0 = *(const bf16x8*)&Vc[l31 * 64 + (((c * 2 + hi) ^ swz) * 8)];
      bf16x8 v1 = *(const bf16x8*)&Vc[(32 + l31) * 64 + (((c * 2 + hi) ^ swz) * 8)];
      oacc[0] = MFMA32(pa[c], v0, oacc[0]);
      oacc[1] = MFMA32(pa[c], v1, oacc[1]);
      racc = MFMA32(pa[c], onesf, racc);
    }
    __builtin_amdgcn_s_setprio(0);

    __syncthreads();  // prefetch landed + guards buffer reuse
  }

  // epilogue: racc[r] = full row-sum for q-row (r&3)+8*(r>>2)+4*hi (same
  // C-layout as oacc) -> fully lane-local normalize, no shuffles.
  const int bb = bh >> 4, hh = bh & 15;
#pragma unroll
  for (int r = 0; r < 16; ++r) {
    int qrow = (r & 3) + 8 * (r >> 2) + 4 * hi;
    float inv = 1.0f / racc[r];
    int pos = qt * 256 + w * 32 + qrow;
    size_t base = ((size_t)bb * SEQ + pos) * EMB + hh * HD;
    o[base + l31] = (bf16)(oacc[0][r] * inv);
    o[base + 32 + l31] = (bf16)(oacc[1][r] * inv);
  }
}

// ---------------------------------------------------------------------------
// Workspace layout (<= 64 MiB used):
//   [0, 16M)   qw [b,h,s,d] bf16   (later woT @0..2M after attn)
//   [16M,32M)  kw;  [32M,48M) vw [b,h,d,s]
//   [48M,64M)  phase1-2: wqkvT (6M) + cosT/sinT; phase3-4: ow bf16 (16M)
// d_out (33.5 MB f32) doubles as xb scratch (16.8 MB bf16) in phases 1-2.
// ---------------------------------------------------------------------------
extern "C" void kernel_launch(void* const* d_in, const int* in_sizes, int n_in,
                              void* d_out, int out_size, void* d_ws, size_t ws_size,
                              hipStream_t stream) {
  const float* x_raw = (const float*)d_in[0];
  const float* wqkv_raw = (const float*)d_in[1];
  const float* bqkv = (const float*)d_in[2];
  const float* wo_raw = (const float*)d_in[3];
  const float* bo = (const float*)d_in[4];
  float* out = (float*)d_out;

  char* ws = (char*)d_ws;
  bf16* qw = (bf16*)(ws);                       // 16 MiB
  bf16* kw = (bf16*)(ws + 16777216);            // 16 MiB
  bf16* vw = (bf16*)(ws + 33554432);            // 16 MiB
  bf16* wqkvT = (bf16*)(ws + 50331648);         // 6 MiB (phase 1-2)
  float* cosT = (float*)(ws + 56623104);        // 256 KiB (phase 1-2)
  float* sinT = (float*)(ws + 56885248);        // 256 KiB (phase 1-2)
  bf16* ow = (bf16*)(ws + 50331648);            // 16 MiB (phase 3-4, overlays above)
  bf16* woT = (bf16*)(ws);                      // 2 MiB (phase 3.5-4, overlays qw)
  bf16* xb = (bf16*)d_out;                      // 16.8 MiB scratch in d_out (phase 1-2)

  static bool attr_set = false;
  if (!attr_set) {
    (void)hipFuncSetAttribute((const void*)qkv128_kernel,
                              hipFuncAttributeMaxDynamicSharedMemorySize, 163840);
    (void)hipFuncSetAttribute((const void*)outproj128_kernel,
                              hipFuncAttributeMaxDynamicSharedMemorySize, 163840);
    attr_set = true;
  }

  prep_kernel<<<11520, 256, 0, stream>>>(x_raw, xb, wqkv_raw, wqkvT, cosT, sinT);

  qkv128_kernel<<<dim3((BATCH * SEQ / 128) * (F3 / 256)), 512, 147456, stream>>>(
      xb, wqkvT, bqkv, qw, kw, vw, cosT, sinT);
  attn32_kernel<<<dim3(BATCH * NH * (SEQ / 256)), 512, 0, stream>>>(qw, kw, vw, ow);

  transpose_f32_bf16<<<dim3(EMB / 32, EMB / 32), 256, 0, stream>>>(wo_raw, woT, EMB, EMB);
  outproj128_kernel<<<dim3((BATCH * SEQ / 128) * (EMB / 256)), 512, 147456, stream>>>(
      ow, woT, bo, out);
}